// Round 15
// baseline (3272.107 us; speedup 1.0000x reference)
//
#include <hip/hip_runtime.h>
#include <math.h>

typedef __attribute__((ext_vector_type(8))) short short8v;   // 8 bf16
typedef __attribute__((ext_vector_type(4))) float f32x4;     // 4 f32 acc

constexpr int Bn = 64;
constexpr int Tn = 512;
constexpr int Hn = 768;
constexpr int RTn = Bn * Tn;               // 32768 rows

constexpr int NPROD = 24;                  // col-blocks per group
constexpr int NGRP  = 8;                   // batch groups (8 batches each)
constexpr int SLOTS = 4;                   // publish ring depth
constexpr int GSTR  = NPROD * 512;         // floats per group per slot
constexpr int SSTR  = NGRP * GSTR;         // floats per slot
constexpr int PITCH = 792;                 // plane row pitch (ushorts)
constexpr int PSZ   = 16 * PITCH;          // plane size (ushorts) = 12672

// workspace offsets (in floats)
constexpr size_t OFF_XP    = 0;
constexpr size_t OFF_H12   = OFF_XP  + (size_t)RTn * Hn;
constexpr size_t OFF_TAGX  = OFF_H12 + (size_t)RTn * Hn;
constexpr size_t OFF_C12   = OFF_TAGX + (size_t)RTn;
constexpr size_t OFF_PUB   = OFF_C12  + Hn;

__device__ inline unsigned short f2bf(float f) {
    union { float f; unsigned u; } v{f};
    unsigned r = v.u + 0x7FFF + ((v.u >> 16) & 1);   // RNE
    return (unsigned short)(r >> 16);
}
__device__ inline float bf2f(unsigned short h) {
    union { unsigned u; float f; } v; v.u = ((unsigned)h) << 16; return v.f;
}

// ---------------------------------------------------------------------------
__global__ void __launch_bounds__(256) c12_kernel(const float* __restrict__ Whh12,
                                                  const float* __restrict__ hinit,
                                                  const float* __restrict__ b12,
                                                  float* __restrict__ c12) {
    int j = blockIdx.x * 256 + threadIdx.x;
    if (j >= Hn) return;
    float s = b12[j];
    const float* row = Whh12 + (size_t)j * Hn;
    for (int e = 0; e < Hn; ++e) s += row[e] * hinit[e];
    c12[j] = s;
}

// ---------------------------------------------------------------------------
__global__ void __launch_bounds__(256) tagx_kernel(const float* __restrict__ bert,
                                                   const float* __restrict__ Wtag,
                                                   const float* __restrict__ btag,
                                                   float* __restrict__ tagx) {
    int r = blockIdx.x * 4 + (threadIdx.x >> 6);
    int lane = threadIdx.x & 63;
    const float* wx = Wtag + 2 * Hn;
    const float* row = bert + (size_t)r * Hn;
    float s = 0.f;
    for (int e = lane; e < Hn; e += 64) s += row[e] * wx[e];
    #pragma unroll
    for (int m = 1; m < 64; m <<= 1) s += __shfl_xor(s, m, 64);
    if (lane == 0) tagx[r] = s + btag[0];
}

// ---------------------------------------------------------------------------
// Precompute GEMM via split-bf16 MFMA (validated R11): cols 0..767 -> xp;
// cols 768..1535 -> h12 = tanh(acc + c12). 128x128 tile, BK=64, 256 thr.
__global__ void __launch_bounds__(256, 2) gemm_pre_mfma(
        const float* __restrict__ bert,
        const float* __restrict__ Wih11, const float* __restrict__ Wih12,
        const float* __restrict__ b11, const float* __restrict__ c12,
        float* __restrict__ xp, float* __restrict__ h12) {
    __shared__ unsigned short Ahi[128][72], Alo[128][72];
    __shared__ unsigned short Bhi[128][72], Blo[128][72];
    const int tid  = threadIdx.x;
    const int wv   = tid >> 6, lane = tid & 63;
    const int mt   = blockIdx.x / 12, nt = blockIdx.x % 12;
    const int r0   = mt * 128;
    const bool second = (nt >= 6);
    const float* W = second ? Wih12 : Wih11;
    const int jb   = (second ? nt - 6 : nt) * 128;

    f32x4 acc[8][2] = {};
    for (int e0 = 0; e0 < Hn; e0 += 64) {
        __syncthreads();
        #pragma unroll
        for (int i = 0; i < 8; ++i) {
            int flat = tid + i * 256;               // 0..2047 float4 units
            int row  = flat >> 4, c4 = (flat & 15) * 4;
            float4 va = *(const float4*)(bert + (size_t)(r0 + row) * Hn + e0 + c4);
            float4 vb = *(const float4*)(W    + (size_t)(jb + row) * Hn + e0 + c4);
            float fa[4] = {va.x, va.y, va.z, va.w};
            float fb[4] = {vb.x, vb.y, vb.z, vb.w};
            unsigned long long uah = 0, ual = 0, ubh = 0, ubl = 0;
            #pragma unroll
            for (int e = 0; e < 4; ++e) {
                unsigned short h = f2bf(fa[e]);
                unsigned short l = f2bf(fa[e] - bf2f(h));
                uah |= (unsigned long long)h << (16 * e);
                ual |= (unsigned long long)l << (16 * e);
                h = f2bf(fb[e]);
                l = f2bf(fb[e] - bf2f(h));
                ubh |= (unsigned long long)h << (16 * e);
                ubl |= (unsigned long long)l << (16 * e);
            }
            *(unsigned long long*)&Ahi[row][c4] = uah;
            *(unsigned long long*)&Alo[row][c4] = ual;
            *(unsigned long long*)&Bhi[row][c4] = ubh;
            *(unsigned long long*)&Blo[row][c4] = ubl;
        }
        __syncthreads();
        #pragma unroll
        for (int kt = 0; kt < 2; ++kt) {
            const int ko  = kt * 32 + (lane >> 4) * 8;
            const int nr0 = wv * 32 + (lane & 15);
            short8v bh0 = __builtin_bit_cast(short8v, *(const uint4*)&Bhi[nr0][ko]);
            short8v bl0 = __builtin_bit_cast(short8v, *(const uint4*)&Blo[nr0][ko]);
            short8v bh1 = __builtin_bit_cast(short8v, *(const uint4*)&Bhi[nr0 + 16][ko]);
            short8v bl1 = __builtin_bit_cast(short8v, *(const uint4*)&Blo[nr0 + 16][ko]);
            #pragma unroll
            for (int m = 0; m < 8; ++m) {
                const int ar = m * 16 + (lane & 15);
                short8v ah = __builtin_bit_cast(short8v, *(const uint4*)&Ahi[ar][ko]);
                short8v al = __builtin_bit_cast(short8v, *(const uint4*)&Alo[ar][ko]);
                acc[m][0] = __builtin_amdgcn_mfma_f32_16x16x32_bf16(ah, bh0, acc[m][0], 0, 0, 0);
                acc[m][0] = __builtin_amdgcn_mfma_f32_16x16x32_bf16(al, bh0, acc[m][0], 0, 0, 0);
                acc[m][0] = __builtin_amdgcn_mfma_f32_16x16x32_bf16(ah, bl0, acc[m][0], 0, 0, 0);
                acc[m][1] = __builtin_amdgcn_mfma_f32_16x16x32_bf16(ah, bh1, acc[m][1], 0, 0, 0);
                acc[m][1] = __builtin_amdgcn_mfma_f32_16x16x32_bf16(al, bh1, acc[m][1], 0, 0, 0);
                acc[m][1] = __builtin_amdgcn_mfma_f32_16x16x32_bf16(ah, bl1, acc[m][1], 0, 0, 0);
            }
        }
    }
    const int nl = lane & 15, rs = lane >> 4;
    #pragma unroll
    for (int ntf = 0; ntf < 2; ++ntf) {
        int lcol = jb + wv * 32 + ntf * 16 + nl;
        float bias = second ? c12[lcol] : b11[lcol];
        #pragma unroll
        for (int m = 0; m < 8; ++m) {
            #pragma unroll
            for (int r = 0; r < 4; ++r) {
                int grow = r0 + m * 16 + rs * 4 + r;
                float v = acc[m][ntf][r] + bias;
                if (second) h12[(size_t)grow * Hn + lcol] = tanhf(v);
                else        xp [(size_t)grow * Hn + lcol] = v;
            }
        }
    }
}

// ---------------------------------------------------------------------------
// Dataflow scan v10 = flagless self-sequenced exchange.
// Packets (u64, single-copy atomic): [15:0]=h1hi [31:16]=h1lo [47:32]=h2hi
// [63:52]=h2lo[15:4] [51:48]=seq nibble. Discovery = the gather itself:
// each thread bulk-loads its 12 packets (MLP), validates nibbles, re-polls
// only pending. No flags, no barrier A: planes hazard covered by barrier C
// (all plane reads for t precede C(t); scatter for t+1 follows own C(t)).
// Ring depth 4 proof: publish(t+1) => gathered t => all published t =>
// all finished gather(t-1) => nobody reads slot t-3 = (t+1)&3.
// 2 barriers/step. Gate uses stride-4 k-coverage (bank-conflict-free).
__global__ void __launch_bounds__(512, 2) scan_kernel(
        const float* __restrict__ xp, const float* __restrict__ h12,
        const float* __restrict__ tagx,
        const float* __restrict__ Whh11, const float* __restrict__ Wih21,
        const float* __restrict__ Whh21, const float* __restrict__ b21,
        const float* __restrict__ Wtag,
        float* __restrict__ pub, float* __restrict__ out) {
    __shared__ unsigned short planes[4 * PSZ];   // h1hi,h1lo,h2hi,h2lo 101.4 KB
    __shared__ float redbuf[8][4][64][4];        // 32 KB
    __shared__ float wt1[Hn], wt2[Hn];           // 6 KB
    __shared__ float tagbuf[8];

    const int tid  = threadIdx.x;
    const int wv   = tid >> 6;          // wave 0..7
    const int lane = tid & 63;
    const int bid  = blockIdx.x;
    const int g    = bid & 7;           // group (XCD round-robin heuristic)
    const int prod = bid >> 3;          // col-block 0..23

    // loop-invariant: B-fragments (hi/lo bf16), 36 frags = 144 VGPR
    short8v wb[3][3][2][2];             // [mat][ktl][nt][hi/lo]
    {
        #pragma unroll
        for (int mt = 0; mt < 3; ++mt) {
            const float* Wmat = (mt == 0) ? Whh11 : (mt == 1) ? Wih21 : Whh21;
            #pragma unroll
            for (int ktl = 0; ktl < 3; ++ktl) {
                #pragma unroll
                for (int nt = 0; nt < 2; ++nt) {
                    int gcol = prod * 32 + nt * 16 + (lane & 15);
                    int k0   = (wv * 3 + ktl) * 32 + (lane >> 4) * 8;
                    const float* p = Wmat + (size_t)gcol * Hn + k0;
                    float4 f0 = *(const float4*)p;
                    float4 f1 = *(const float4*)(p + 4);
                    float fv[8] = {f0.x, f0.y, f0.z, f0.w, f1.x, f1.y, f1.z, f1.w};
                    union { short8v v; unsigned short u[8]; } hi, lo;
                    #pragma unroll
                    for (int i = 0; i < 8; ++i) {
                        unsigned short h = f2bf(fv[i]);
                        hi.u[i] = h;
                        lo.u[i] = f2bf(fv[i] - bf2f(h));
                    }
                    wb[mt][ktl][nt][0] = hi.v;
                    wb[mt][ktl][nt][1] = lo.v;
                }
            }
        }
    }
    for (int i = tid; i < Hn; i += 512) { wt1[i] = Wtag[i]; wt2[i] = Wtag[Hn + i]; }
    const int ecol = prod * 32 + (tid & 31);     // epilogue col for tid<256
    const float bias21 = b21[ecol];

    // zero planes once (rows 8-15 stay zero; rows 0-7 overwritten each step)
    for (int i = tid; i < 4 * PSZ / 2; i += 512) ((unsigned int*)planes)[i] = 0u;

    float* outO   = out;
    float* outH2  = out + RTn;
    float* outTag = out + RTn + (size_t)RTn * Hn;
    float h2c = 0.f;                    // fp32 carry (tid<256)
    __syncthreads();

    for (int t = 0; t < Tn; ++t) {
        // prefetch (independent of exchange)
        float xpv = 0.f, h12pv = 0.f, tgxv = 0.f;
        if (tid < 256) {
            int m = tid >> 5;
            size_t rr = (size_t)(g * 8 + m) * Tn + t;
            xpv   = xp  [rr * Hn + ecol];
            h12pv = h12 [rr * Hn + ecol];
            tgxv  = tagx[rr];
        }

        // flagless gather: bulk MLP load, nibble-validate, re-poll pending
        {
            const unsigned long long* pubc =
                (const unsigned long long*)(pub + (size_t)(t & 3) * SSTR + g * GSTR);
            const unsigned sq = (unsigned)(t & 15);
            unsigned long long v[12];
            #pragma unroll
            for (int i = 0; i < 12; ++i)
                v[i] = __hip_atomic_load(pubc + tid + i * 512, __ATOMIC_RELAXED,
                                         __HIP_MEMORY_SCOPE_AGENT);
            unsigned pend = 0;
            #pragma unroll
            for (int i = 0; i < 12; ++i)
                if ((unsigned)((v[i] >> 48) & 15ull) != sq) pend |= (1u << i);
            while (__builtin_expect(pend != 0, 0)) {
                __builtin_amdgcn_s_sleep(1);
                #pragma unroll
                for (int i = 0; i < 12; ++i)
                    if (pend & (1u << i))
                        v[i] = __hip_atomic_load(pubc + tid + i * 512,
                                                 __ATOMIC_RELAXED,
                                                 __HIP_MEMORY_SCOPE_AGENT);
                unsigned np = 0;
                #pragma unroll
                for (int i = 0; i < 12; ++i)
                    if ((pend & (1u << i)) &&
                        (unsigned)((v[i] >> 48) & 15ull) != sq) np |= (1u << i);
                pend = np;
            }
            // scatter bf16 fields to planes (seq nibble masked out of h2lo)
            #pragma unroll
            for (int i = 0; i < 12; ++i) {
                int idx = tid + i * 512;
                int p = idx >> 8, rem = idx & 255;
                int m = rem >> 5, jc = rem & 31;
                int base = m * PITCH + p * 32 + jc;
                unsigned long long u = v[i];
                planes[0 * PSZ + base] = (unsigned short)(u & 0xFFFF);
                planes[1 * PSZ + base] = (unsigned short)((u >> 16) & 0xFFFF);
                planes[2 * PSZ + base] = (unsigned short)((u >> 32) & 0xFFFF);
                planes[3 * PSZ + base] = (unsigned short)((u >> 48) & 0xFFF0);
            }
        }
        __syncthreads();   // B: planes staged

        // gate: wave wv = batch wv; lane covers k = part*256 + lane*4
        // (8B lane stride -> 2-way bank aliasing = free)
        {
            float s = 0.f;
            #pragma unroll
            for (int part = 0; part < 3; ++part) {
                const int k = part * 256 + lane * 4;
                const int off = wv * PITCH + k;
                unsigned long long u1h = *(const unsigned long long*)&planes[0 * PSZ + off];
                unsigned long long u1l = *(const unsigned long long*)&planes[1 * PSZ + off];
                unsigned long long u2h = *(const unsigned long long*)&planes[2 * PSZ + off];
                unsigned long long u2l = *(const unsigned long long*)&planes[3 * PSZ + off];
                #pragma unroll
                for (int e = 0; e < 4; ++e) {
                    float h1 = bf2f((unsigned short)(u1h >> (16 * e)))
                             + bf2f((unsigned short)(u1l >> (16 * e)));
                    float h2 = bf2f((unsigned short)(u2h >> (16 * e)))
                             + bf2f((unsigned short)(u2l >> (16 * e)));
                    s = fmaf(h1, wt1[k + e], s);
                    s = fmaf(h2, wt2[k + e], s);
                }
            }
            #pragma unroll
            for (int mm = 1; mm < 64; mm <<= 1) s += __shfl_xor(s, mm, 64);
            if (lane == 0) tagbuf[wv] = s;
        }

        // MFMA matvec: wave wv covers K-tiles wv*3..+3
        {
            f32x4 a00 = {0.f,0.f,0.f,0.f}, a01 = {0.f,0.f,0.f,0.f};
            f32x4 a10 = {0.f,0.f,0.f,0.f}, a11v = {0.f,0.f,0.f,0.f};
            const int ar = (lane & 15) * PITCH + (lane >> 4) * 8;
            #pragma unroll
            for (int ktl = 0; ktl < 3; ++ktl) {
                const int ko = (wv * 3 + ktl) * 32 + ar;
                short8v h1h = __builtin_bit_cast(short8v, *(const uint4*)&planes[0 * PSZ + ko]);
                short8v h1l = __builtin_bit_cast(short8v, *(const uint4*)&planes[1 * PSZ + ko]);
                short8v h2h = __builtin_bit_cast(short8v, *(const uint4*)&planes[2 * PSZ + ko]);
                short8v h2l = __builtin_bit_cast(short8v, *(const uint4*)&planes[3 * PSZ + ko]);
                a00 = __builtin_amdgcn_mfma_f32_16x16x32_bf16(h1h, wb[0][ktl][0][0], a00, 0, 0, 0);
                a00 = __builtin_amdgcn_mfma_f32_16x16x32_bf16(h1l, wb[0][ktl][0][0], a00, 0, 0, 0);
                a00 = __builtin_amdgcn_mfma_f32_16x16x32_bf16(h1h, wb[0][ktl][0][1], a00, 0, 0, 0);
                a01 = __builtin_amdgcn_mfma_f32_16x16x32_bf16(h1h, wb[0][ktl][1][0], a01, 0, 0, 0);
                a01 = __builtin_amdgcn_mfma_f32_16x16x32_bf16(h1l, wb[0][ktl][1][0], a01, 0, 0, 0);
                a01 = __builtin_amdgcn_mfma_f32_16x16x32_bf16(h1h, wb[0][ktl][1][1], a01, 0, 0, 0);
                a10 = __builtin_amdgcn_mfma_f32_16x16x32_bf16(h1h, wb[1][ktl][0][0], a10, 0, 0, 0);
                a10 = __builtin_amdgcn_mfma_f32_16x16x32_bf16(h1l, wb[1][ktl][0][0], a10, 0, 0, 0);
                a10 = __builtin_amdgcn_mfma_f32_16x16x32_bf16(h1h, wb[1][ktl][0][1], a10, 0, 0, 0);
                a11v = __builtin_amdgcn_mfma_f32_16x16x32_bf16(h1h, wb[1][ktl][1][0], a11v, 0, 0, 0);
                a11v = __builtin_amdgcn_mfma_f32_16x16x32_bf16(h1l, wb[1][ktl][1][0], a11v, 0, 0, 0);
                a11v = __builtin_amdgcn_mfma_f32_16x16x32_bf16(h1h, wb[1][ktl][1][1], a11v, 0, 0, 0);
                a10 = __builtin_amdgcn_mfma_f32_16x16x32_bf16(h2h, wb[2][ktl][0][0], a10, 0, 0, 0);
                a10 = __builtin_amdgcn_mfma_f32_16x16x32_bf16(h2l, wb[2][ktl][0][0], a10, 0, 0, 0);
                a10 = __builtin_amdgcn_mfma_f32_16x16x32_bf16(h2h, wb[2][ktl][0][1], a10, 0, 0, 0);
                a11v = __builtin_amdgcn_mfma_f32_16x16x32_bf16(h2h, wb[2][ktl][1][0], a11v, 0, 0, 0);
                a11v = __builtin_amdgcn_mfma_f32_16x16x32_bf16(h2l, wb[2][ktl][1][0], a11v, 0, 0, 0);
                a11v = __builtin_amdgcn_mfma_f32_16x16x32_bf16(h2h, wb[2][ktl][1][1], a11v, 0, 0, 0);
            }
            *(f32x4*)&redbuf[wv][0][lane][0] = a00;
            *(f32x4*)&redbuf[wv][1][lane][0] = a01;
            *(f32x4*)&redbuf[wv][2][lane][0] = a10;
            *(f32x4*)&redbuf[wv][3][lane][0] = a11v;
        }
        __syncthreads();   // C: redbuf + tagbuf ready; also gates next scatter

        // epilogue: tid<256 = (batch m, col jc); publish seq-tagged u64
        if (tid < 256) {
            int m = tid >> 5, jc = tid & 31;
            int n = jc & 15, nt = jc >> 4;
            int rl = (m >> 2) * 16 + n, rg = m & 3;
            float f11 = 0.f, f21 = 0.f;
            #pragma unroll
            for (int w = 0; w < 8; ++w) {
                f11 += redbuf[w][nt][rl][rg];
                f21 += redbuf[w][2 + nt][rl][rg];
            }
            float tg = tagbuf[m] + tgxv;
            float o  = 1.f / (1.f + expf(-tg));
            float h11v = tanhf(xpv + f11);
            float h21v = tanhf(f21 + bias21);
            float h1nv = h11v * (1.f - o) + h12pv * o;
            float h2nv = h2c * (1.f - o) + h21v * o;
            h2c = h2nv;
            unsigned short h1h = f2bf(h1nv);
            unsigned short h1l = f2bf(h1nv - bf2f(h1h));
            unsigned short h2h = f2bf(h2nv);
            unsigned short h2l = f2bf(h2nv - bf2f(h2h));
            unsigned short h2q = (unsigned short)((h2l & 0xFFF0)
                                                  | (unsigned)((t + 1) & 15));
            unsigned long long u = (unsigned long long)h1h
                                 | ((unsigned long long)h1l << 16)
                                 | ((unsigned long long)h2h << 32)
                                 | ((unsigned long long)h2q << 48);
            unsigned long long* pn =
                (unsigned long long*)(pub + (size_t)((t + 1) & 3) * SSTR + g * GSTR)
                + prod * 256 + m * 32 + jc;
            __hip_atomic_store(pn, u, __ATOMIC_RELAXED, __HIP_MEMORY_SCOPE_AGENT);
            // outputs — never on the inter-block critical chain
            size_t rr = (size_t)(g * 8 + m) * Tn + t;
            outH2[rr * Hn + ecol] = h2nv;
            if (jc == 0 && prod == 0) { outO[rr] = o; outTag[rr] = tg; }
        }
        // no barrier here: next scatter is safe after this thread's C(t)
    }
}

// ---------------------------------------------------------------------------
extern "C" void kernel_launch(void* const* d_in, const int* in_sizes, int n_in,
                              void* d_out, int out_size, void* d_ws, size_t ws_size,
                              hipStream_t stream) {
    const float* bert  = (const float*)d_in[0];
    const float* Wih11 = (const float*)d_in[1];
    const float* Whh11 = (const float*)d_in[2];
    const float* b11   = (const float*)d_in[3];
    const float* Wih12 = (const float*)d_in[4];
    const float* Whh12 = (const float*)d_in[5];
    const float* b12   = (const float*)d_in[6];
    const float* Wih21 = (const float*)d_in[7];
    const float* Whh21 = (const float*)d_in[8];
    const float* b21   = (const float*)d_in[9];
    const float* Wtag  = (const float*)d_in[10];
    const float* btag  = (const float*)d_in[11];
    const float* hinit = (const float*)d_in[12];
    float* ws = (float*)d_ws;
    float* xp    = ws + OFF_XP;
    float* h12   = ws + OFF_H12;
    float* tagx  = ws + OFF_TAGX;
    float* c12   = ws + OFF_C12;
    float* pub   = ws + OFF_PUB;
    float* out   = (float*)d_out;

    // zero publish ring (slot 0 = initial h=0 state, seq nibble 0)
    hipMemsetAsync(pub, 0, (size_t)SLOTS * SSTR * sizeof(float), stream);

    c12_kernel<<<3, 256, 0, stream>>>(Whh12, hinit, b12, c12);
    gemm_pre_mfma<<<256 * 12, 256, 0, stream>>>(bert, Wih11, Wih12, b11, c12,
                                                xp, h12);
    tagx_kernel<<<RTn / 4, 256, 0, stream>>>(bert, Wtag, btag, tagx);

    void* params[] = { &xp, &h12, &tagx, &Whh11, &Wih21, &Whh21, &b21, &Wtag,
                       &pub, &out };
    hipLaunchCooperativeKernel((void*)scan_kernel, dim3(192), dim3(512),
                               params, 0, stream);
}

// Round 16
// 2829.353 us; speedup vs baseline: 1.1565x; 1.1565x over previous
//
#include <hip/hip_runtime.h>
#include <math.h>

typedef __attribute__((ext_vector_type(8))) short short8v;   // 8 bf16
typedef __attribute__((ext_vector_type(4))) float f32x4;     // 4 f32 acc

constexpr int Bn = 64;
constexpr int Tn = 512;
constexpr int Hn = 768;
constexpr int RTn = Bn * Tn;               // 32768 rows

constexpr int NPROD = 24;                  // col-blocks per group
constexpr int NGRP  = 8;                   // batch groups (8 batches each)
constexpr int SLOTS = 4;                   // publish ring depth
constexpr int GSTR  = NPROD * 512;         // floats per group per slot
constexpr int SSTR  = NGRP * GSTR;         // floats per slot
constexpr int FSTR  = 32;                  // flag stride (ints) = 128B line
constexpr int PITCH = 792;                 // plane row pitch (ushorts)
constexpr int PSZ   = 16 * PITCH;          // plane size (ushorts) = 12672

// workspace offsets (in floats)
constexpr size_t OFF_XP    = 0;
constexpr size_t OFF_H12   = OFF_XP  + (size_t)RTn * Hn;
constexpr size_t OFF_TAGX  = OFF_H12 + (size_t)RTn * Hn;
constexpr size_t OFF_C12   = OFF_TAGX + (size_t)RTn;
constexpr size_t OFF_PUB   = OFF_C12  + Hn;
constexpr size_t OFF_FLAGS = OFF_PUB  + (size_t)SLOTS * SSTR;  // int region

__device__ inline unsigned short f2bf(float f) {
    union { float f; unsigned u; } v{f};
    unsigned r = v.u + 0x7FFF + ((v.u >> 16) & 1);   // RNE
    return (unsigned short)(r >> 16);
}
__device__ inline float bf2f(unsigned short h) {
    union { unsigned u; float f; } v; v.u = ((unsigned)h) << 16; return v.f;
}

// ---------------------------------------------------------------------------
__global__ void __launch_bounds__(256) c12_kernel(const float* __restrict__ Whh12,
                                                  const float* __restrict__ hinit,
                                                  const float* __restrict__ b12,
                                                  float* __restrict__ c12) {
    int j = blockIdx.x * 256 + threadIdx.x;
    if (j >= Hn) return;
    float s = b12[j];
    const float* row = Whh12 + (size_t)j * Hn;
    for (int e = 0; e < Hn; ++e) s += row[e] * hinit[e];
    c12[j] = s;
}

// ---------------------------------------------------------------------------
__global__ void __launch_bounds__(256) tagx_kernel(const float* __restrict__ bert,
                                                   const float* __restrict__ Wtag,
                                                   const float* __restrict__ btag,
                                                   float* __restrict__ tagx) {
    int r = blockIdx.x * 4 + (threadIdx.x >> 6);
    int lane = threadIdx.x & 63;
    const float* wx = Wtag + 2 * Hn;
    const float* row = bert + (size_t)r * Hn;
    float s = 0.f;
    for (int e = lane; e < Hn; e += 64) s += row[e] * wx[e];
    #pragma unroll
    for (int m = 1; m < 64; m <<= 1) s += __shfl_xor(s, m, 64);
    if (lane == 0) tagx[r] = s + btag[0];
}

// ---------------------------------------------------------------------------
// Precompute GEMM via split-bf16 MFMA (validated R11): cols 0..767 -> xp;
// cols 768..1535 -> h12 = tanh(acc + c12). 128x128 tile, BK=64, 256 thr.
__global__ void __launch_bounds__(256, 2) gemm_pre_mfma(
        const float* __restrict__ bert,
        const float* __restrict__ Wih11, const float* __restrict__ Wih12,
        const float* __restrict__ b11, const float* __restrict__ c12,
        float* __restrict__ xp, float* __restrict__ h12) {
    __shared__ unsigned short Ahi[128][72], Alo[128][72];
    __shared__ unsigned short Bhi[128][72], Blo[128][72];
    const int tid  = threadIdx.x;
    const int wv   = tid >> 6, lane = tid & 63;
    const int mt   = blockIdx.x / 12, nt = blockIdx.x % 12;
    const int r0   = mt * 128;
    const bool second = (nt >= 6);
    const float* W = second ? Wih12 : Wih11;
    const int jb   = (second ? nt - 6 : nt) * 128;

    f32x4 acc[8][2] = {};
    for (int e0 = 0; e0 < Hn; e0 += 64) {
        __syncthreads();
        #pragma unroll
        for (int i = 0; i < 8; ++i) {
            int flat = tid + i * 256;               // 0..2047 float4 units
            int row  = flat >> 4, c4 = (flat & 15) * 4;
            float4 va = *(const float4*)(bert + (size_t)(r0 + row) * Hn + e0 + c4);
            float4 vb = *(const float4*)(W    + (size_t)(jb + row) * Hn + e0 + c4);
            float fa[4] = {va.x, va.y, va.z, va.w};
            float fb[4] = {vb.x, vb.y, vb.z, vb.w};
            unsigned long long uah = 0, ual = 0, ubh = 0, ubl = 0;
            #pragma unroll
            for (int e = 0; e < 4; ++e) {
                unsigned short h = f2bf(fa[e]);
                unsigned short l = f2bf(fa[e] - bf2f(h));
                uah |= (unsigned long long)h << (16 * e);
                ual |= (unsigned long long)l << (16 * e);
                h = f2bf(fb[e]);
                l = f2bf(fb[e] - bf2f(h));
                ubh |= (unsigned long long)h << (16 * e);
                ubl |= (unsigned long long)l << (16 * e);
            }
            *(unsigned long long*)&Ahi[row][c4] = uah;
            *(unsigned long long*)&Alo[row][c4] = ual;
            *(unsigned long long*)&Bhi[row][c4] = ubh;
            *(unsigned long long*)&Blo[row][c4] = ubl;
        }
        __syncthreads();
        #pragma unroll
        for (int kt = 0; kt < 2; ++kt) {
            const int ko  = kt * 32 + (lane >> 4) * 8;
            const int nr0 = wv * 32 + (lane & 15);
            short8v bh0 = __builtin_bit_cast(short8v, *(const uint4*)&Bhi[nr0][ko]);
            short8v bl0 = __builtin_bit_cast(short8v, *(const uint4*)&Blo[nr0][ko]);
            short8v bh1 = __builtin_bit_cast(short8v, *(const uint4*)&Bhi[nr0 + 16][ko]);
            short8v bl1 = __builtin_bit_cast(short8v, *(const uint4*)&Blo[nr0 + 16][ko]);
            #pragma unroll
            for (int m = 0; m < 8; ++m) {
                const int ar = m * 16 + (lane & 15);
                short8v ah = __builtin_bit_cast(short8v, *(const uint4*)&Ahi[ar][ko]);
                short8v al = __builtin_bit_cast(short8v, *(const uint4*)&Alo[ar][ko]);
                acc[m][0] = __builtin_amdgcn_mfma_f32_16x16x32_bf16(ah, bh0, acc[m][0], 0, 0, 0);
                acc[m][0] = __builtin_amdgcn_mfma_f32_16x16x32_bf16(al, bh0, acc[m][0], 0, 0, 0);
                acc[m][0] = __builtin_amdgcn_mfma_f32_16x16x32_bf16(ah, bl0, acc[m][0], 0, 0, 0);
                acc[m][1] = __builtin_amdgcn_mfma_f32_16x16x32_bf16(ah, bh1, acc[m][1], 0, 0, 0);
                acc[m][1] = __builtin_amdgcn_mfma_f32_16x16x32_bf16(al, bh1, acc[m][1], 0, 0, 0);
                acc[m][1] = __builtin_amdgcn_mfma_f32_16x16x32_bf16(ah, bl1, acc[m][1], 0, 0, 0);
            }
        }
    }
    const int nl = lane & 15, rs = lane >> 4;
    #pragma unroll
    for (int ntf = 0; ntf < 2; ++ntf) {
        int lcol = jb + wv * 32 + ntf * 16 + nl;
        float bias = second ? c12[lcol] : b11[lcol];
        #pragma unroll
        for (int m = 0; m < 8; ++m) {
            #pragma unroll
            for (int r = 0; r < 4; ++r) {
                int grow = r0 + m * 16 + rs * 4 + r;
                float v = acc[m][ntf][r] + bias;
                if (second) h12[(size_t)grow * Hn + lcol] = tanhf(v);
                else        xp [(size_t)grow * Hn + lcol] = v;
            }
        }
    }
}

// ---------------------------------------------------------------------------
// Dataflow scan v8 (R13, measured best: 2.31 ms scan). Packet u64:
// [15:0]=h1hi [31:16]=h1lo [47:32]=h2hi [63:52]=h2lo[15:4] [51:48]=seq.
// Flags = fast-path discovery (24 pollers, barrier A); per-packet seq
// nibble = correctness backstop (stale words detected + re-fetched).
__global__ void __launch_bounds__(512, 2) scan_kernel(
        const float* __restrict__ xp, const float* __restrict__ h12,
        const float* __restrict__ tagx,
        const float* __restrict__ Whh11, const float* __restrict__ Wih21,
        const float* __restrict__ Whh21, const float* __restrict__ b21,
        const float* __restrict__ Wtag,
        float* __restrict__ pub, int* __restrict__ flags,
        float* __restrict__ out) {
    __shared__ unsigned short planes[4 * PSZ];   // h1hi,h1lo,h2hi,h2lo 101.4 KB
    __shared__ float redbuf[8][4][64][4];        // 32 KB
    __shared__ float wt1[Hn], wt2[Hn];           // 6 KB
    __shared__ float tagbuf[8];

    const int tid  = threadIdx.x;
    const int wv   = tid >> 6;          // wave 0..7
    const int lane = tid & 63;
    const int bid  = blockIdx.x;
    const int g    = bid & 7;           // group (XCD round-robin heuristic)
    const int prod = bid >> 3;          // col-block 0..23

    // loop-invariant: B-fragments (hi/lo bf16), 36 frags = 144 VGPR
    short8v wb[3][3][2][2];             // [mat][ktl][nt][hi/lo]
    {
        #pragma unroll
        for (int mt = 0; mt < 3; ++mt) {
            const float* Wmat = (mt == 0) ? Whh11 : (mt == 1) ? Wih21 : Whh21;
            #pragma unroll
            for (int ktl = 0; ktl < 3; ++ktl) {
                #pragma unroll
                for (int nt = 0; nt < 2; ++nt) {
                    int gcol = prod * 32 + nt * 16 + (lane & 15);
                    int k0   = (wv * 3 + ktl) * 32 + (lane >> 4) * 8;
                    const float* p = Wmat + (size_t)gcol * Hn + k0;
                    float4 f0 = *(const float4*)p;
                    float4 f1 = *(const float4*)(p + 4);
                    float fv[8] = {f0.x, f0.y, f0.z, f0.w, f1.x, f1.y, f1.z, f1.w};
                    union { short8v v; unsigned short u[8]; } hi, lo;
                    #pragma unroll
                    for (int i = 0; i < 8; ++i) {
                        unsigned short h = f2bf(fv[i]);
                        hi.u[i] = h;
                        lo.u[i] = f2bf(fv[i] - bf2f(h));
                    }
                    wb[mt][ktl][nt][0] = hi.v;
                    wb[mt][ktl][nt][1] = lo.v;
                }
            }
        }
    }
    for (int i = tid; i < Hn; i += 512) { wt1[i] = Wtag[i]; wt2[i] = Wtag[Hn + i]; }
    const int ecol = prod * 32 + (tid & 31);     // epilogue col for tid<256
    const float bias21 = b21[ecol];

    // zero planes once (rows 8-15 stay zero; rows 0-7 overwritten each step)
    for (int i = tid; i < 4 * PSZ / 2; i += 512) ((unsigned int*)planes)[i] = 0u;

    float* outO   = out;
    float* outH2  = out + RTn;
    float* outTag = out + RTn + (size_t)RTn * Hn;
    int* myflag = flags + (g * NPROD + prod) * FSTR;
    float h2c = 0.f;                    // fp32 carry (tid<256)
    __syncthreads();

    for (int t = 0; t < Tn; ++t) {
        // flag-independent prefetch
        float xpv = 0.f, h12pv = 0.f, tgxv = 0.f;
        if (tid < 256) {
            int m = tid >> 5;
            size_t rr = (size_t)(g * 8 + m) * Tn + t;
            xpv   = xp  [rr * Hn + ecol];
            h12pv = h12 [rr * Hn + ecol];
            tgxv  = tagx[rr];
        }

        // spin: 24 parallel pollers (fast-path discovery only)
        if (tid < NPROD) {
            const int* f = flags + (g * NPROD + tid) * FSTR;
            while (__hip_atomic_load(f, __ATOMIC_RELAXED,
                                     __HIP_MEMORY_SCOPE_AGENT) < t)
                __builtin_amdgcn_s_sleep(2);
        }
        __syncthreads();   // A

        // bulk gather 48 KB (MLP), validate seq nibbles, re-fetch stale only
        {
            const unsigned long long* pubc =
                (const unsigned long long*)(pub + (size_t)(t & 3) * SSTR + g * GSTR);
            const unsigned sq = (unsigned)(t & 15);
            unsigned long long v[12];
            #pragma unroll
            for (int i = 0; i < 12; ++i)
                v[i] = __hip_atomic_load(pubc + tid + i * 512, __ATOMIC_RELAXED,
                                         __HIP_MEMORY_SCOPE_AGENT);
            unsigned pend = 0;
            #pragma unroll
            for (int i = 0; i < 12; ++i)
                if ((unsigned)((v[i] >> 48) & 15ull) != sq) pend |= (1u << i);
            while (__builtin_expect(pend != 0, 0)) {
                __builtin_amdgcn_s_sleep(1);
                #pragma unroll
                for (int i = 0; i < 12; ++i)
                    if (pend & (1u << i))
                        v[i] = __hip_atomic_load(pubc + tid + i * 512,
                                                 __ATOMIC_RELAXED,
                                                 __HIP_MEMORY_SCOPE_AGENT);
                unsigned np = 0;
                #pragma unroll
                for (int i = 0; i < 12; ++i)
                    if ((pend & (1u << i)) &&
                        (unsigned)((v[i] >> 48) & 15ull) != sq) np |= (1u << i);
                pend = np;
            }
            // scatter bf16 fields to planes (seq nibble masked out of h2lo)
            #pragma unroll
            for (int i = 0; i < 12; ++i) {
                int idx = tid + i * 512;
                int p = idx >> 8, rem = idx & 255;
                int m = rem >> 5, jc = rem & 31;
                int base = m * PITCH + p * 32 + jc;
                unsigned long long u = v[i];
                planes[0 * PSZ + base] = (unsigned short)(u & 0xFFFF);
                planes[1 * PSZ + base] = (unsigned short)((u >> 16) & 0xFFFF);
                planes[2 * PSZ + base] = (unsigned short)((u >> 32) & 0xFFFF);
                planes[3 * PSZ + base] = (unsigned short)((u >> 48) & 0xFFF0);
            }
        }
        __syncthreads();   // B: planes staged

        // gate: wave wv = batch wv; lane covers k = lane*12 .. +12
        {
            const int kb = lane * 12;
            float s = 0.f;
            #pragma unroll
            for (int part = 0; part < 3; ++part) {
                int off = wv * PITCH + kb + part * 4;
                unsigned long long u1h = *(const unsigned long long*)&planes[0 * PSZ + off];
                unsigned long long u1l = *(const unsigned long long*)&planes[1 * PSZ + off];
                unsigned long long u2h = *(const unsigned long long*)&planes[2 * PSZ + off];
                unsigned long long u2l = *(const unsigned long long*)&planes[3 * PSZ + off];
                #pragma unroll
                for (int e = 0; e < 4; ++e) {
                    int k = kb + part * 4 + e;
                    float h1 = bf2f((unsigned short)(u1h >> (16 * e)))
                             + bf2f((unsigned short)(u1l >> (16 * e)));
                    float h2 = bf2f((unsigned short)(u2h >> (16 * e)))
                             + bf2f((unsigned short)(u2l >> (16 * e)));
                    s = fmaf(h1, wt1[k], s);
                    s = fmaf(h2, wt2[k], s);
                }
            }
            #pragma unroll
            for (int mm = 1; mm < 64; mm <<= 1) s += __shfl_xor(s, mm, 64);
            if (lane == 0) tagbuf[wv] = s;
        }

        // MFMA matvec: wave wv covers K-tiles wv*3..+3
        {
            f32x4 a00 = {0.f,0.f,0.f,0.f}, a01 = {0.f,0.f,0.f,0.f};
            f32x4 a10 = {0.f,0.f,0.f,0.f}, a11v = {0.f,0.f,0.f,0.f};
            const int ar = (lane & 15) * PITCH + (lane >> 4) * 8;
            #pragma unroll
            for (int ktl = 0; ktl < 3; ++ktl) {
                const int ko = (wv * 3 + ktl) * 32 + ar;
                short8v h1h = __builtin_bit_cast(short8v, *(const uint4*)&planes[0 * PSZ + ko]);
                short8v h1l = __builtin_bit_cast(short8v, *(const uint4*)&planes[1 * PSZ + ko]);
                short8v h2h = __builtin_bit_cast(short8v, *(const uint4*)&planes[2 * PSZ + ko]);
                short8v h2l = __builtin_bit_cast(short8v, *(const uint4*)&planes[3 * PSZ + ko]);
                a00 = __builtin_amdgcn_mfma_f32_16x16x32_bf16(h1h, wb[0][ktl][0][0], a00, 0, 0, 0);
                a00 = __builtin_amdgcn_mfma_f32_16x16x32_bf16(h1l, wb[0][ktl][0][0], a00, 0, 0, 0);
                a00 = __builtin_amdgcn_mfma_f32_16x16x32_bf16(h1h, wb[0][ktl][0][1], a00, 0, 0, 0);
                a01 = __builtin_amdgcn_mfma_f32_16x16x32_bf16(h1h, wb[0][ktl][1][0], a01, 0, 0, 0);
                a01 = __builtin_amdgcn_mfma_f32_16x16x32_bf16(h1l, wb[0][ktl][1][0], a01, 0, 0, 0);
                a01 = __builtin_amdgcn_mfma_f32_16x16x32_bf16(h1h, wb[0][ktl][1][1], a01, 0, 0, 0);
                a10 = __builtin_amdgcn_mfma_f32_16x16x32_bf16(h1h, wb[1][ktl][0][0], a10, 0, 0, 0);
                a10 = __builtin_amdgcn_mfma_f32_16x16x32_bf16(h1l, wb[1][ktl][0][0], a10, 0, 0, 0);
                a10 = __builtin_amdgcn_mfma_f32_16x16x32_bf16(h1h, wb[1][ktl][0][1], a10, 0, 0, 0);
                a11v = __builtin_amdgcn_mfma_f32_16x16x32_bf16(h1h, wb[1][ktl][1][0], a11v, 0, 0, 0);
                a11v = __builtin_amdgcn_mfma_f32_16x16x32_bf16(h1l, wb[1][ktl][1][0], a11v, 0, 0, 0);
                a11v = __builtin_amdgcn_mfma_f32_16x16x32_bf16(h1h, wb[1][ktl][1][1], a11v, 0, 0, 0);
                a10 = __builtin_amdgcn_mfma_f32_16x16x32_bf16(h2h, wb[2][ktl][0][0], a10, 0, 0, 0);
                a10 = __builtin_amdgcn_mfma_f32_16x16x32_bf16(h2l, wb[2][ktl][0][0], a10, 0, 0, 0);
                a10 = __builtin_amdgcn_mfma_f32_16x16x32_bf16(h2h, wb[2][ktl][0][1], a10, 0, 0, 0);
                a11v = __builtin_amdgcn_mfma_f32_16x16x32_bf16(h2h, wb[2][ktl][1][0], a11v, 0, 0, 0);
                a11v = __builtin_amdgcn_mfma_f32_16x16x32_bf16(h2l, wb[2][ktl][1][0], a11v, 0, 0, 0);
                a11v = __builtin_amdgcn_mfma_f32_16x16x32_bf16(h2h, wb[2][ktl][1][1], a11v, 0, 0, 0);
            }
            *(f32x4*)&redbuf[wv][0][lane][0] = a00;
            *(f32x4*)&redbuf[wv][1][lane][0] = a01;
            *(f32x4*)&redbuf[wv][2][lane][0] = a10;
            *(f32x4*)&redbuf[wv][3][lane][0] = a11v;
        }
        __syncthreads();   // C: redbuf + tagbuf ready

        // epilogue: tid<256 = (batch m, col jc); publish seq-tagged u64
        float o = 0.f, tg = 0.f, h2nv = 0.f;
        if (tid < 256) {
            int m = tid >> 5, jc = tid & 31;
            int n = jc & 15, nt = jc >> 4;
            int rl = (m >> 2) * 16 + n, rg = m & 3;
            float f11 = 0.f, f21 = 0.f;
            #pragma unroll
            for (int w = 0; w < 8; ++w) {
                f11 += redbuf[w][nt][rl][rg];
                f21 += redbuf[w][2 + nt][rl][rg];
            }
            tg = tagbuf[m] + tgxv;
            o  = 1.f / (1.f + expf(-tg));
            float h11v = tanhf(xpv + f11);
            float h21v = tanhf(f21 + bias21);
            float h1nv = h11v * (1.f - o) + h12pv * o;
            h2nv = h2c * (1.f - o) + h21v * o;
            h2c = h2nv;
            unsigned short h1h = f2bf(h1nv);
            unsigned short h1l = f2bf(h1nv - bf2f(h1h));
            unsigned short h2h = f2bf(h2nv);
            unsigned short h2l = f2bf(h2nv - bf2f(h2h));
            unsigned short h2q = (unsigned short)((h2l & 0xFFF0)
                                                  | (unsigned)((t + 1) & 15));
            unsigned long long u = (unsigned long long)h1h
                                 | ((unsigned long long)h1l << 16)
                                 | ((unsigned long long)h2h << 32)
                                 | ((unsigned long long)h2q << 48);
            unsigned long long* pn =
                (unsigned long long*)(pub + (size_t)((t + 1) & 3) * SSTR + g * GSTR)
                + prod * 256 + m * 32 + jc;
            __hip_atomic_store(pn, u, __ATOMIC_RELAXED, __HIP_MEMORY_SCOPE_AGENT);
        }
        __syncthreads();   // D: drains publish stores (fast-path ordering)
        if (tid == 0)
            __hip_atomic_store(myflag, t + 1, __ATOMIC_RELAXED,
                               __HIP_MEMORY_SCOPE_AGENT);
        // outputs after the flag — off the inter-block critical chain
        if (tid < 256) {
            int m = tid >> 5;
            size_t rr = (size_t)(g * 8 + m) * Tn + t;
            outH2[rr * Hn + ecol] = h2nv;
            if ((tid & 31) == 0 && prod == 0) { outO[rr] = o; outTag[rr] = tg; }
        }
    }
}

// ---------------------------------------------------------------------------
extern "C" void kernel_launch(void* const* d_in, const int* in_sizes, int n_in,
                              void* d_out, int out_size, void* d_ws, size_t ws_size,
                              hipStream_t stream) {
    const float* bert  = (const float*)d_in[0];
    const float* Wih11 = (const float*)d_in[1];
    const float* Whh11 = (const float*)d_in[2];
    const float* b11   = (const float*)d_in[3];
    const float* Wih12 = (const float*)d_in[4];
    const float* Whh12 = (const float*)d_in[5];
    const float* b12   = (const float*)d_in[6];
    const float* Wih21 = (const float*)d_in[7];
    const float* Whh21 = (const float*)d_in[8];
    const float* b21   = (const float*)d_in[9];
    const float* Wtag  = (const float*)d_in[10];
    const float* btag  = (const float*)d_in[11];
    const float* hinit = (const float*)d_in[12];
    float* ws = (float*)d_ws;
    float* xp    = ws + OFF_XP;
    float* h12   = ws + OFF_H12;
    float* tagx  = ws + OFF_TAGX;
    float* c12   = ws + OFF_C12;
    float* pub   = ws + OFF_PUB;
    int*   flags = (int*)(ws + OFF_FLAGS);
    float* out   = (float*)d_out;

    // zero publish ring (slot 0 = initial h=0 state, seq nibble 0) and flags
    hipMemsetAsync(pub,   0, (size_t)SLOTS * SSTR * sizeof(float), stream);
    hipMemsetAsync(flags, 0, NGRP * NPROD * FSTR * sizeof(int), stream);

    c12_kernel<<<3, 256, 0, stream>>>(Whh12, hinit, b12, c12);
    gemm_pre_mfma<<<256 * 12, 256, 0, stream>>>(bert, Wih11, Wih12, b11, c12,
                                                xp, h12);
    tagx_kernel<<<RTn / 4, 256, 0, stream>>>(bert, Wtag, btag, tagx);

    void* params[] = { &xp, &h12, &tagx, &Whh11, &Wih21, &Whh21, &b21, &Wtag,
                       &pub, &flags, &out };
    hipLaunchCooperativeKernel((void*)scan_kernel, dim3(192), dim3(512),
                               params, 0, stream);
}

// Round 17
// 2663.880 us; speedup vs baseline: 1.2283x; 1.0621x over previous
//
#include <hip/hip_runtime.h>
#include <math.h>

typedef __attribute__((ext_vector_type(8))) short short8v;   // 8 bf16
typedef __attribute__((ext_vector_type(4))) float f32x4;     // 4 f32 acc
typedef unsigned long long u64;

constexpr int Bn = 64;
constexpr int Tn = 512;
constexpr int Hn = 768;
constexpr int RTn = Bn * Tn;               // 32768 rows

constexpr int NPROD = 24;                  // col-blocks per group
constexpr int NGRP  = 8;                   // batch groups (8 batches each)
constexpr int SLOTS = 4;                   // publish ring depth
constexpr int GSTR  = NPROD * 512;         // floats per group per slot
constexpr int SSTR  = NGRP * GSTR;         // floats per slot
constexpr int FSTR  = 32;                  // flag stride (ints) = 128B line
constexpr int PITCH = 792;                 // plane row pitch (ushorts)
constexpr int PSZ   = 16 * PITCH;          // plane size (ushorts) = 12672

// workspace offsets (in floats)
constexpr size_t OFF_XP    = 0;
constexpr size_t OFF_H12   = OFF_XP  + (size_t)RTn * Hn;
constexpr size_t OFF_TAGX  = OFF_H12 + (size_t)RTn * Hn;
constexpr size_t OFF_C12   = OFF_TAGX + (size_t)RTn;
constexpr size_t OFF_PUB   = OFF_C12  + Hn;
constexpr size_t OFF_FLAGS = OFF_PUB  + (size_t)SLOTS * SSTR;  // int region
// optional pre-split region (guarded by ws_size at runtime)
constexpr size_t OFF_BHI   = OFF_FLAGS + (size_t)NGRP * NPROD * FSTR;
constexpr size_t OFF_BLO   = OFF_BHI + (size_t)RTn * Hn / 2;   // ushort planes
constexpr size_t OFF_WHI   = OFF_BLO + (size_t)RTn * Hn / 2;
constexpr size_t OFF_WLO   = OFF_WHI + (size_t)2 * Hn * Hn / 2;
constexpr size_t NEED_FLT  = OFF_WLO + (size_t)2 * Hn * Hn / 2;

__device__ inline unsigned short f2bf(float f) {
    union { float f; unsigned u; } v{f};
    unsigned r = v.u + 0x7FFF + ((v.u >> 16) & 1);   // RNE
    return (unsigned short)(r >> 16);
}
__device__ inline float bf2f(unsigned short h) {
    union { unsigned u; float f; } v; v.u = ((unsigned)h) << 16; return v.f;
}

// ---------------------------------------------------------------------------
__global__ void __launch_bounds__(256) c12_kernel(const float* __restrict__ Whh12,
                                                  const float* __restrict__ hinit,
                                                  const float* __restrict__ b12,
                                                  float* __restrict__ c12) {
    int j = blockIdx.x * 256 + threadIdx.x;
    if (j >= Hn) return;
    float s = b12[j];
    const float* row = Whh12 + (size_t)j * Hn;
    for (int e = 0; e < Hn; ++e) s += row[e] * hinit[e];
    c12[j] = s;
}

// ---------------------------------------------------------------------------
__global__ void __launch_bounds__(256) tagx_kernel(const float* __restrict__ bert,
                                                   const float* __restrict__ Wtag,
                                                   const float* __restrict__ btag,
                                                   float* __restrict__ tagx) {
    int r = blockIdx.x * 4 + (threadIdx.x >> 6);
    int lane = threadIdx.x & 63;
    const float* wx = Wtag + 2 * Hn;
    const float* row = bert + (size_t)r * Hn;
    float s = 0.f;
    for (int e = lane; e < Hn; e += 64) s += row[e] * wx[e];
    #pragma unroll
    for (int m = 1; m < 64; m <<= 1) s += __shfl_xor(s, m, 64);
    if (lane == 0) tagx[r] = s + btag[0];
}

// ---------------------------------------------------------------------------
// One-time hi/lo bf16 split of bert (25165824 elements, float4 granular).
__global__ void __launch_bounds__(256) split_bert(const float4* __restrict__ in,
                                                  u64* __restrict__ hi,
                                                  u64* __restrict__ lo) {
    const int stride = gridDim.x * 256;
    for (int u = blockIdx.x * 256 + threadIdx.x; u < RTn * Hn / 4; u += stride) {
        float4 v = in[u];
        float f[4] = {v.x, v.y, v.z, v.w};
        u64 uh = 0, ul = 0;
        #pragma unroll
        for (int e = 0; e < 4; ++e) {
            unsigned short h = f2bf(f[e]);
            unsigned short l = f2bf(f[e] - bf2f(h));
            uh |= (u64)h << (16 * e);
            ul |= (u64)l << (16 * e);
        }
        hi[u] = uh; lo[u] = ul;
    }
}

// ---------------------------------------------------------------------------
// One-time hi/lo split of Wih11 (mat0) and Wih12 (mat1): 2 x 768x768.
__global__ void __launch_bounds__(256) split_w(const float* __restrict__ W0,
                                               const float* __restrict__ W1,
                                               u64* __restrict__ whi,
                                               u64* __restrict__ wlo) {
    int u = blockIdx.x * 256 + threadIdx.x;            // 0..294911
    constexpr int UPM = Hn * Hn / 4;                    // 147456 units/matrix
    if (u >= 2 * UPM) return;
    int mat = (u >= UPM) ? 1 : 0;
    int loc = u - mat * UPM;
    float4 v = ((const float4*)(mat ? W1 : W0))[loc];
    float f[4] = {v.x, v.y, v.z, v.w};
    u64 uh = 0, ul = 0;
    #pragma unroll
    for (int e = 0; e < 4; ++e) {
        unsigned short h = f2bf(f[e]);
        unsigned short l = f2bf(f[e] - bf2f(h));
        uh |= (u64)h << (16 * e);
        ul |= (u64)l << (16 * e);
    }
    whi[u] = uh; wlo[u] = ul;
}

// ---------------------------------------------------------------------------
// Precompute GEMM v2: identical tiling/math to the validated R11 kernel, but
// operands come pre-split (bhi/blo, whi/wlo) => staging is pure u64 copies,
// no per-iteration f2bf VALU.
__global__ void __launch_bounds__(256, 2) gemm_pre_mfma_v2(
        const unsigned short* __restrict__ bhi, const unsigned short* __restrict__ blo,
        const unsigned short* __restrict__ whi, const unsigned short* __restrict__ wlo,
        const float* __restrict__ b11, const float* __restrict__ c12,
        float* __restrict__ xp, float* __restrict__ h12) {
    __shared__ unsigned short Ahi[128][72], Alo[128][72];
    __shared__ unsigned short Bhi[128][72], Blo[128][72];
    const int tid  = threadIdx.x;
    const int wv   = tid >> 6, lane = tid & 63;
    const int mt   = blockIdx.x / 12, nt = blockIdx.x % 12;
    const int r0   = mt * 128;
    const bool second = (nt >= 6);
    const int jb   = (second ? nt - 6 : nt) * 128;
    const size_t matbase = second ? (size_t)Hn * Hn : 0;

    f32x4 acc[8][2] = {};
    for (int e0 = 0; e0 < Hn; e0 += 64) {
        __syncthreads();
        #pragma unroll
        for (int i = 0; i < 8; ++i) {
            int flat = tid + i * 256;               // 0..2047 4-elem units
            int row  = flat >> 4, c4 = (flat & 15) * 4;
            size_t aoff = (size_t)(r0 + row) * Hn + e0 + c4;
            size_t boff = matbase + (size_t)(jb + row) * Hn + e0 + c4;
            *(u64*)&Ahi[row][c4] = *(const u64*)(bhi + aoff);
            *(u64*)&Alo[row][c4] = *(const u64*)(blo + aoff);
            *(u64*)&Bhi[row][c4] = *(const u64*)(whi + boff);
            *(u64*)&Blo[row][c4] = *(const u64*)(wlo + boff);
        }
        __syncthreads();
        #pragma unroll
        for (int kt = 0; kt < 2; ++kt) {
            const int ko  = kt * 32 + (lane >> 4) * 8;
            const int nr0 = wv * 32 + (lane & 15);
            short8v bh0 = __builtin_bit_cast(short8v, *(const uint4*)&Bhi[nr0][ko]);
            short8v bl0 = __builtin_bit_cast(short8v, *(const uint4*)&Blo[nr0][ko]);
            short8v bh1 = __builtin_bit_cast(short8v, *(const uint4*)&Bhi[nr0 + 16][ko]);
            short8v bl1 = __builtin_bit_cast(short8v, *(const uint4*)&Blo[nr0 + 16][ko]);
            #pragma unroll
            for (int m = 0; m < 8; ++m) {
                const int ar = m * 16 + (lane & 15);
                short8v ah = __builtin_bit_cast(short8v, *(const uint4*)&Ahi[ar][ko]);
                short8v al = __builtin_bit_cast(short8v, *(const uint4*)&Alo[ar][ko]);
                acc[m][0] = __builtin_amdgcn_mfma_f32_16x16x32_bf16(ah, bh0, acc[m][0], 0, 0, 0);
                acc[m][0] = __builtin_amdgcn_mfma_f32_16x16x32_bf16(al, bh0, acc[m][0], 0, 0, 0);
                acc[m][0] = __builtin_amdgcn_mfma_f32_16x16x32_bf16(ah, bl0, acc[m][0], 0, 0, 0);
                acc[m][1] = __builtin_amdgcn_mfma_f32_16x16x32_bf16(ah, bh1, acc[m][1], 0, 0, 0);
                acc[m][1] = __builtin_amdgcn_mfma_f32_16x16x32_bf16(al, bh1, acc[m][1], 0, 0, 0);
                acc[m][1] = __builtin_amdgcn_mfma_f32_16x16x32_bf16(ah, bl1, acc[m][1], 0, 0, 0);
            }
        }
    }
    const int nl = lane & 15, rs = lane >> 4;
    #pragma unroll
    for (int ntf = 0; ntf < 2; ++ntf) {
        int lcol = jb + wv * 32 + ntf * 16 + nl;
        float bias = second ? c12[lcol] : b11[lcol];
        #pragma unroll
        for (int m = 0; m < 8; ++m) {
            #pragma unroll
            for (int r = 0; r < 4; ++r) {
                int grow = r0 + m * 16 + rs * 4 + r;
                float v = acc[m][ntf][r] + bias;
                if (second) h12[(size_t)grow * Hn + lcol] = tanhf(v);
                else        xp [(size_t)grow * Hn + lcol] = v;
            }
        }
    }
}

// ---------------------------------------------------------------------------
// Precompute GEMM (R11/R16 fallback): converts operands in-kernel.
__global__ void __launch_bounds__(256, 2) gemm_pre_mfma(
        const float* __restrict__ bert,
        const float* __restrict__ Wih11, const float* __restrict__ Wih12,
        const float* __restrict__ b11, const float* __restrict__ c12,
        float* __restrict__ xp, float* __restrict__ h12) {
    __shared__ unsigned short Ahi[128][72], Alo[128][72];
    __shared__ unsigned short Bhi[128][72], Blo[128][72];
    const int tid  = threadIdx.x;
    const int wv   = tid >> 6, lane = tid & 63;
    const int mt   = blockIdx.x / 12, nt = blockIdx.x % 12;
    const int r0   = mt * 128;
    const bool second = (nt >= 6);
    const float* W = second ? Wih12 : Wih11;
    const int jb   = (second ? nt - 6 : nt) * 128;

    f32x4 acc[8][2] = {};
    for (int e0 = 0; e0 < Hn; e0 += 64) {
        __syncthreads();
        #pragma unroll
        for (int i = 0; i < 8; ++i) {
            int flat = tid + i * 256;
            int row  = flat >> 4, c4 = (flat & 15) * 4;
            float4 va = *(const float4*)(bert + (size_t)(r0 + row) * Hn + e0 + c4);
            float4 vb = *(const float4*)(W    + (size_t)(jb + row) * Hn + e0 + c4);
            float fa[4] = {va.x, va.y, va.z, va.w};
            float fb[4] = {vb.x, vb.y, vb.z, vb.w};
            u64 uah = 0, ual = 0, ubh = 0, ubl = 0;
            #pragma unroll
            for (int e = 0; e < 4; ++e) {
                unsigned short h = f2bf(fa[e]);
                unsigned short l = f2bf(fa[e] - bf2f(h));
                uah |= (u64)h << (16 * e);
                ual |= (u64)l << (16 * e);
                h = f2bf(fb[e]);
                l = f2bf(fb[e] - bf2f(h));
                ubh |= (u64)h << (16 * e);
                ubl |= (u64)l << (16 * e);
            }
            *(u64*)&Ahi[row][c4] = uah;
            *(u64*)&Alo[row][c4] = ual;
            *(u64*)&Bhi[row][c4] = ubh;
            *(u64*)&Blo[row][c4] = ubl;
        }
        __syncthreads();
        #pragma unroll
        for (int kt = 0; kt < 2; ++kt) {
            const int ko  = kt * 32 + (lane >> 4) * 8;
            const int nr0 = wv * 32 + (lane & 15);
            short8v bh0 = __builtin_bit_cast(short8v, *(const uint4*)&Bhi[nr0][ko]);
            short8v bl0 = __builtin_bit_cast(short8v, *(const uint4*)&Blo[nr0][ko]);
            short8v bh1 = __builtin_bit_cast(short8v, *(const uint4*)&Bhi[nr0 + 16][ko]);
            short8v bl1 = __builtin_bit_cast(short8v, *(const uint4*)&Blo[nr0 + 16][ko]);
            #pragma unroll
            for (int m = 0; m < 8; ++m) {
                const int ar = m * 16 + (lane & 15);
                short8v ah = __builtin_bit_cast(short8v, *(const uint4*)&Ahi[ar][ko]);
                short8v al = __builtin_bit_cast(short8v, *(const uint4*)&Alo[ar][ko]);
                acc[m][0] = __builtin_amdgcn_mfma_f32_16x16x32_bf16(ah, bh0, acc[m][0], 0, 0, 0);
                acc[m][0] = __builtin_amdgcn_mfma_f32_16x16x32_bf16(al, bh0, acc[m][0], 0, 0, 0);
                acc[m][0] = __builtin_amdgcn_mfma_f32_16x16x32_bf16(ah, bl0, acc[m][0], 0, 0, 0);
                acc[m][1] = __builtin_amdgcn_mfma_f32_16x16x32_bf16(ah, bh1, acc[m][1], 0, 0, 0);
                acc[m][1] = __builtin_amdgcn_mfma_f32_16x16x32_bf16(al, bh1, acc[m][1], 0, 0, 0);
                acc[m][1] = __builtin_amdgcn_mfma_f32_16x16x32_bf16(ah, bl1, acc[m][1], 0, 0, 0);
            }
        }
    }
    const int nl = lane & 15, rs = lane >> 4;
    #pragma unroll
    for (int ntf = 0; ntf < 2; ++ntf) {
        int lcol = jb + wv * 32 + ntf * 16 + nl;
        float bias = second ? c12[lcol] : b11[lcol];
        #pragma unroll
        for (int m = 0; m < 8; ++m) {
            #pragma unroll
            for (int r = 0; r < 4; ++r) {
                int grow = r0 + m * 16 + rs * 4 + r;
                float v = acc[m][ntf][r] + bias;
                if (second) h12[(size_t)grow * Hn + lcol] = tanhf(v);
                else        xp [(size_t)grow * Hn + lcol] = v;
            }
        }
    }
}

// ---------------------------------------------------------------------------
// Dataflow scan (R13/R16, measured best: 2.30 ms). Packet u64:
// [15:0]=h1hi [31:16]=h1lo [47:32]=h2hi [63:52]=h2lo[15:4] [51:48]=seq.
// Flags = fast-path discovery (24 pollers, barrier A); per-packet seq
// nibble = correctness backstop (stale words detected + re-fetched).
__global__ void __launch_bounds__(512, 2) scan_kernel(
        const float* __restrict__ xp, const float* __restrict__ h12,
        const float* __restrict__ tagx,
        const float* __restrict__ Whh11, const float* __restrict__ Wih21,
        const float* __restrict__ Whh21, const float* __restrict__ b21,
        const float* __restrict__ Wtag,
        float* __restrict__ pub, int* __restrict__ flags,
        float* __restrict__ out) {
    __shared__ unsigned short planes[4 * PSZ];   // h1hi,h1lo,h2hi,h2lo 101.4 KB
    __shared__ float redbuf[8][4][64][4];        // 32 KB
    __shared__ float wt1[Hn], wt2[Hn];           // 6 KB
    __shared__ float tagbuf[8];

    const int tid  = threadIdx.x;
    const int wv   = tid >> 6;          // wave 0..7
    const int lane = tid & 63;
    const int bid  = blockIdx.x;
    const int g    = bid & 7;           // group (XCD round-robin heuristic)
    const int prod = bid >> 3;          // col-block 0..23

    // loop-invariant: B-fragments (hi/lo bf16), 36 frags = 144 VGPR
    short8v wb[3][3][2][2];             // [mat][ktl][nt][hi/lo]
    {
        #pragma unroll
        for (int mt = 0; mt < 3; ++mt) {
            const float* Wmat = (mt == 0) ? Whh11 : (mt == 1) ? Wih21 : Whh21;
            #pragma unroll
            for (int ktl = 0; ktl < 3; ++ktl) {
                #pragma unroll
                for (int nt = 0; nt < 2; ++nt) {
                    int gcol = prod * 32 + nt * 16 + (lane & 15);
                    int k0   = (wv * 3 + ktl) * 32 + (lane >> 4) * 8;
                    const float* p = Wmat + (size_t)gcol * Hn + k0;
                    float4 f0 = *(const float4*)p;
                    float4 f1 = *(const float4*)(p + 4);
                    float fv[8] = {f0.x, f0.y, f0.z, f0.w, f1.x, f1.y, f1.z, f1.w};
                    union { short8v v; unsigned short u[8]; } hi, lo;
                    #pragma unroll
                    for (int i = 0; i < 8; ++i) {
                        unsigned short h = f2bf(fv[i]);
                        hi.u[i] = h;
                        lo.u[i] = f2bf(fv[i] - bf2f(h));
                    }
                    wb[mt][ktl][nt][0] = hi.v;
                    wb[mt][ktl][nt][1] = lo.v;
                }
            }
        }
    }
    for (int i = tid; i < Hn; i += 512) { wt1[i] = Wtag[i]; wt2[i] = Wtag[Hn + i]; }
    const int ecol = prod * 32 + (tid & 31);     // epilogue col for tid<256
    const float bias21 = b21[ecol];

    // zero planes once (rows 8-15 stay zero; rows 0-7 overwritten each step)
    for (int i = tid; i < 4 * PSZ / 2; i += 512) ((unsigned int*)planes)[i] = 0u;

    float* outO   = out;
    float* outH2  = out + RTn;
    float* outTag = out + RTn + (size_t)RTn * Hn;
    int* myflag = flags + (g * NPROD + prod) * FSTR;
    float h2c = 0.f;                    // fp32 carry (tid<256)
    __syncthreads();

    for (int t = 0; t < Tn; ++t) {
        // flag-independent prefetch
        float xpv = 0.f, h12pv = 0.f, tgxv = 0.f;
        if (tid < 256) {
            int m = tid >> 5;
            size_t rr = (size_t)(g * 8 + m) * Tn + t;
            xpv   = xp  [rr * Hn + ecol];
            h12pv = h12 [rr * Hn + ecol];
            tgxv  = tagx[rr];
        }

        // spin: 24 parallel pollers (fast-path discovery only)
        if (tid < NPROD) {
            const int* f = flags + (g * NPROD + tid) * FSTR;
            while (__hip_atomic_load(f, __ATOMIC_RELAXED,
                                     __HIP_MEMORY_SCOPE_AGENT) < t)
                __builtin_amdgcn_s_sleep(2);
        }
        __syncthreads();   // A

        // bulk gather 48 KB (MLP), validate seq nibbles, re-fetch stale only
        {
            const u64* pubc =
                (const u64*)(pub + (size_t)(t & 3) * SSTR + g * GSTR);
            const unsigned sq = (unsigned)(t & 15);
            u64 v[12];
            #pragma unroll
            for (int i = 0; i < 12; ++i)
                v[i] = __hip_atomic_load(pubc + tid + i * 512, __ATOMIC_RELAXED,
                                         __HIP_MEMORY_SCOPE_AGENT);
            unsigned pend = 0;
            #pragma unroll
            for (int i = 0; i < 12; ++i)
                if ((unsigned)((v[i] >> 48) & 15ull) != sq) pend |= (1u << i);
            while (__builtin_expect(pend != 0, 0)) {
                __builtin_amdgcn_s_sleep(1);
                #pragma unroll
                for (int i = 0; i < 12; ++i)
                    if (pend & (1u << i))
                        v[i] = __hip_atomic_load(pubc + tid + i * 512,
                                                 __ATOMIC_RELAXED,
                                                 __HIP_MEMORY_SCOPE_AGENT);
                unsigned np = 0;
                #pragma unroll
                for (int i = 0; i < 12; ++i)
                    if ((pend & (1u << i)) &&
                        (unsigned)((v[i] >> 48) & 15ull) != sq) np |= (1u << i);
                pend = np;
            }
            // scatter bf16 fields to planes (seq nibble masked out of h2lo)
            #pragma unroll
            for (int i = 0; i < 12; ++i) {
                int idx = tid + i * 512;
                int p = idx >> 8, rem = idx & 255;
                int m = rem >> 5, jc = rem & 31;
                int base = m * PITCH + p * 32 + jc;
                u64 u = v[i];
                planes[0 * PSZ + base] = (unsigned short)(u & 0xFFFF);
                planes[1 * PSZ + base] = (unsigned short)((u >> 16) & 0xFFFF);
                planes[2 * PSZ + base] = (unsigned short)((u >> 32) & 0xFFFF);
                planes[3 * PSZ + base] = (unsigned short)((u >> 48) & 0xFFF0);
            }
        }
        __syncthreads();   // B: planes staged

        // gate: wave wv = batch wv; lane covers k = lane*12 .. +12
        {
            const int kb = lane * 12;
            float s = 0.f;
            #pragma unroll
            for (int part = 0; part < 3; ++part) {
                int off = wv * PITCH + kb + part * 4;
                u64 u1h = *(const u64*)&planes[0 * PSZ + off];
                u64 u1l = *(const u64*)&planes[1 * PSZ + off];
                u64 u2h = *(const u64*)&planes[2 * PSZ + off];
                u64 u2l = *(const u64*)&planes[3 * PSZ + off];
                #pragma unroll
                for (int e = 0; e < 4; ++e) {
                    int k = kb + part * 4 + e;
                    float h1 = bf2f((unsigned short)(u1h >> (16 * e)))
                             + bf2f((unsigned short)(u1l >> (16 * e)));
                    float h2 = bf2f((unsigned short)(u2h >> (16 * e)))
                             + bf2f((unsigned short)(u2l >> (16 * e)));
                    s = fmaf(h1, wt1[k], s);
                    s = fmaf(h2, wt2[k], s);
                }
            }
            #pragma unroll
            for (int mm = 1; mm < 64; mm <<= 1) s += __shfl_xor(s, mm, 64);
            if (lane == 0) tagbuf[wv] = s;
        }

        // MFMA matvec: wave wv covers K-tiles wv*3..+3
        {
            f32x4 a00 = {0.f,0.f,0.f,0.f}, a01 = {0.f,0.f,0.f,0.f};
            f32x4 a10 = {0.f,0.f,0.f,0.f}, a11v = {0.f,0.f,0.f,0.f};
            const int ar = (lane & 15) * PITCH + (lane >> 4) * 8;
            #pragma unroll
            for (int ktl = 0; ktl < 3; ++ktl) {
                const int ko = (wv * 3 + ktl) * 32 + ar;
                short8v h1h = __builtin_bit_cast(short8v, *(const uint4*)&planes[0 * PSZ + ko]);
                short8v h1l = __builtin_bit_cast(short8v, *(const uint4*)&planes[1 * PSZ + ko]);
                short8v h2h = __builtin_bit_cast(short8v, *(const uint4*)&planes[2 * PSZ + ko]);
                short8v h2l = __builtin_bit_cast(short8v, *(const uint4*)&planes[3 * PSZ + ko]);
                a00 = __builtin_amdgcn_mfma_f32_16x16x32_bf16(h1h, wb[0][ktl][0][0], a00, 0, 0, 0);
                a00 = __builtin_amdgcn_mfma_f32_16x16x32_bf16(h1l, wb[0][ktl][0][0], a00, 0, 0, 0);
                a00 = __builtin_amdgcn_mfma_f32_16x16x32_bf16(h1h, wb[0][ktl][0][1], a00, 0, 0, 0);
                a01 = __builtin_amdgcn_mfma_f32_16x16x32_bf16(h1h, wb[0][ktl][1][0], a01, 0, 0, 0);
                a01 = __builtin_amdgcn_mfma_f32_16x16x32_bf16(h1l, wb[0][ktl][1][0], a01, 0, 0, 0);
                a01 = __builtin_amdgcn_mfma_f32_16x16x32_bf16(h1h, wb[0][ktl][1][1], a01, 0, 0, 0);
                a10 = __builtin_amdgcn_mfma_f32_16x16x32_bf16(h1h, wb[1][ktl][0][0], a10, 0, 0, 0);
                a10 = __builtin_amdgcn_mfma_f32_16x16x32_bf16(h1l, wb[1][ktl][0][0], a10, 0, 0, 0);
                a10 = __builtin_amdgcn_mfma_f32_16x16x32_bf16(h1h, wb[1][ktl][0][1], a10, 0, 0, 0);
                a11v = __builtin_amdgcn_mfma_f32_16x16x32_bf16(h1h, wb[1][ktl][1][0], a11v, 0, 0, 0);
                a11v = __builtin_amdgcn_mfma_f32_16x16x32_bf16(h1l, wb[1][ktl][1][0], a11v, 0, 0, 0);
                a11v = __builtin_amdgcn_mfma_f32_16x16x32_bf16(h1h, wb[1][ktl][1][1], a11v, 0, 0, 0);
                a10 = __builtin_amdgcn_mfma_f32_16x16x32_bf16(h2h, wb[2][ktl][0][0], a10, 0, 0, 0);
                a10 = __builtin_amdgcn_mfma_f32_16x16x32_bf16(h2l, wb[2][ktl][0][0], a10, 0, 0, 0);
                a10 = __builtin_amdgcn_mfma_f32_16x16x32_bf16(h2h, wb[2][ktl][0][1], a10, 0, 0, 0);
                a11v = __builtin_amdgcn_mfma_f32_16x16x32_bf16(h2h, wb[2][ktl][1][0], a11v, 0, 0, 0);
                a11v = __builtin_amdgcn_mfma_f32_16x16x32_bf16(h2l, wb[2][ktl][1][0], a11v, 0, 0, 0);
                a11v = __builtin_amdgcn_mfma_f32_16x16x32_bf16(h2h, wb[2][ktl][1][1], a11v, 0, 0, 0);
            }
            *(f32x4*)&redbuf[wv][0][lane][0] = a00;
            *(f32x4*)&redbuf[wv][1][lane][0] = a01;
            *(f32x4*)&redbuf[wv][2][lane][0] = a10;
            *(f32x4*)&redbuf[wv][3][lane][0] = a11v;
        }
        __syncthreads();   // C: redbuf + tagbuf ready

        // epilogue: tid<256 = (batch m, col jc); publish seq-tagged u64
        float o = 0.f, tg = 0.f, h2nv = 0.f;
        if (tid < 256) {
            int m = tid >> 5, jc = tid & 31;
            int n = jc & 15, nt = jc >> 4;
            int rl = (m >> 2) * 16 + n, rg = m & 3;
            float f11 = 0.f, f21 = 0.f;
            #pragma unroll
            for (int w = 0; w < 8; ++w) {
                f11 += redbuf[w][nt][rl][rg];
                f21 += redbuf[w][2 + nt][rl][rg];
            }
            tg = tagbuf[m] + tgxv;
            o  = 1.f / (1.f + expf(-tg));
            float h11v = tanhf(xpv + f11);
            float h21v = tanhf(f21 + bias21);
            float h1nv = h11v * (1.f - o) + h12pv * o;
            h2nv = h2c * (1.f - o) + h21v * o;
            h2c = h2nv;
            unsigned short h1h = f2bf(h1nv);
            unsigned short h1l = f2bf(h1nv - bf2f(h1h));
            unsigned short h2h = f2bf(h2nv);
            unsigned short h2l = f2bf(h2nv - bf2f(h2h));
            unsigned short h2q = (unsigned short)((h2l & 0xFFF0)
                                                  | (unsigned)((t + 1) & 15));
            u64 u = (u64)h1h | ((u64)h1l << 16) | ((u64)h2h << 32)
                  | ((u64)h2q << 48);
            u64* pn = (u64*)(pub + (size_t)((t + 1) & 3) * SSTR + g * GSTR)
                    + prod * 256 + m * 32 + jc;
            __hip_atomic_store(pn, u, __ATOMIC_RELAXED, __HIP_MEMORY_SCOPE_AGENT);
        }
        __syncthreads();   // D: drains publish stores (fast-path ordering)
        if (tid == 0)
            __hip_atomic_store(myflag, t + 1, __ATOMIC_RELAXED,
                               __HIP_MEMORY_SCOPE_AGENT);
        // outputs after the flag — off the inter-block critical chain
        if (tid < 256) {
            int m = tid >> 5;
            size_t rr = (size_t)(g * 8 + m) * Tn + t;
            outH2[rr * Hn + ecol] = h2nv;
            if ((tid & 31) == 0 && prod == 0) { outO[rr] = o; outTag[rr] = tg; }
        }
    }
}

// ---------------------------------------------------------------------------
extern "C" void kernel_launch(void* const* d_in, const int* in_sizes, int n_in,
                              void* d_out, int out_size, void* d_ws, size_t ws_size,
                              hipStream_t stream) {
    const float* bert  = (const float*)d_in[0];
    const float* Wih11 = (const float*)d_in[1];
    const float* Whh11 = (const float*)d_in[2];
    const float* b11   = (const float*)d_in[3];
    const float* Wih12 = (const float*)d_in[4];
    const float* Whh12 = (const float*)d_in[5];
    const float* b12   = (const float*)d_in[6];
    const float* Wih21 = (const float*)d_in[7];
    const float* Whh21 = (const float*)d_in[8];
    const float* b21   = (const float*)d_in[9];
    const float* Wtag  = (const float*)d_in[10];
    const float* btag  = (const float*)d_in[11];
    const float* hinit = (const float*)d_in[12];
    float* ws = (float*)d_ws;
    float* xp    = ws + OFF_XP;
    float* h12   = ws + OFF_H12;
    float* tagx  = ws + OFF_TAGX;
    float* c12   = ws + OFF_C12;
    float* pub   = ws + OFF_PUB;
    int*   flags = (int*)(ws + OFF_FLAGS);
    float* out   = (float*)d_out;

    // zero publish ring (slot 0 = initial h=0 state, seq nibble 0) and flags
    hipMemsetAsync(pub,   0, (size_t)SLOTS * SSTR * sizeof(float), stream);
    hipMemsetAsync(flags, 0, NGRP * NPROD * FSTR * sizeof(int), stream);

    c12_kernel<<<3, 256, 0, stream>>>(Whh12, hinit, b12, c12);

    const bool use_split = ws_size >= NEED_FLT * sizeof(float);
    if (use_split) {
        unsigned short* bhi = (unsigned short*)(ws + OFF_BHI);
        unsigned short* blo = (unsigned short*)(ws + OFF_BLO);
        unsigned short* whi = (unsigned short*)(ws + OFF_WHI);
        unsigned short* wlo = (unsigned short*)(ws + OFF_WLO);
        split_bert<<<4096, 256, 0, stream>>>((const float4*)bert,
                                             (u64*)bhi, (u64*)blo);
        split_w<<<1152, 256, 0, stream>>>(Wih11, Wih12, (u64*)whi, (u64*)wlo);
        gemm_pre_mfma_v2<<<256 * 12, 256, 0, stream>>>(bhi, blo, whi, wlo,
                                                       b11, c12, xp, h12);
    } else {
        gemm_pre_mfma<<<256 * 12, 256, 0, stream>>>(bert, Wih11, Wih12, b11,
                                                    c12, xp, h12);
    }
    tagx_kernel<<<RTn / 4, 256, 0, stream>>>(bert, Wtag, btag, tagx);

    void* params[] = { &xp, &h12, &tagx, &Whh11, &Wih21, &Whh21, &b21, &Wtag,
                       &pub, &flags, &out };
    hipLaunchCooperativeKernel((void*)scan_kernel, dim3(192), dim3(512),
                               params, 0, stream);
}

// Round 18
// 2443.796 us; speedup vs baseline: 1.3389x; 1.0901x over previous
//
#include <hip/hip_runtime.h>
#include <math.h>

typedef __attribute__((ext_vector_type(8))) short short8v;   // 8 bf16
typedef __attribute__((ext_vector_type(4))) float f32x4;     // 4 f32 acc
typedef unsigned long long u64;

constexpr int Bn = 64;
constexpr int Tn = 512;
constexpr int Hn = 768;
constexpr int RTn = Bn * Tn;               // 32768 rows

constexpr int NPROD = 24;                  // col-blocks per group
constexpr int NGRP  = 8;                   // batch groups (8 batches each)
constexpr int SLOTS = 4;                   // publish ring depth
constexpr int GSTR  = NPROD * 512;         // floats per group per slot
constexpr int SSTR  = NGRP * GSTR;         // floats per slot
constexpr int FSTR  = 32;                  // flag stride (ints) = 128B line
constexpr int PITCH = 792;                 // plane row pitch (ushorts)
constexpr int PSZ   = 16 * PITCH;          // plane size (ushorts) = 12672

// workspace offsets (in floats)
constexpr size_t OFF_XP    = 0;
constexpr size_t OFF_H12   = OFF_XP  + (size_t)RTn * Hn;
constexpr size_t OFF_TAGX  = OFF_H12 + (size_t)RTn * Hn;
constexpr size_t OFF_C12   = OFF_TAGX + (size_t)RTn;
constexpr size_t OFF_PUB   = OFF_C12  + Hn;
constexpr size_t OFF_FLAGS = OFF_PUB  + (size_t)SLOTS * SSTR;  // int region
constexpr size_t OFF_QCNT  = OFF_FLAGS + (size_t)NGRP * NPROD * FSTR; // 4 ints
// optional pre-split region (guarded by ws_size at runtime)
constexpr size_t OFF_BHI   = OFF_QCNT + 64;
constexpr size_t OFF_BLO   = OFF_BHI + (size_t)RTn * Hn / 2;   // ushort planes
constexpr size_t OFF_WHI   = OFF_BLO + (size_t)RTn * Hn / 2;
constexpr size_t OFF_WLO   = OFF_WHI + (size_t)2 * Hn * Hn / 2;
constexpr size_t NEED_FLT  = OFF_WLO + (size_t)2 * Hn * Hn / 2;

__device__ inline unsigned short f2bf(float f) {
    union { float f; unsigned u; } v{f};
    unsigned r = v.u + 0x7FFF + ((v.u >> 16) & 1);   // RNE
    return (unsigned short)(r >> 16);
}
__device__ inline float bf2f(unsigned short h) {
    union { unsigned u; float f; } v; v.u = ((unsigned)h) << 16; return v.f;
}

struct ScanSh {
    unsigned short planes[4 * PSZ];
    float redbuf[8][4][64][4];
    float wt1[Hn], wt2[Hn];
    float tagbuf[8];
};
struct GemmSh {
    unsigned short Ahi[128][72], Alo[128][72], Bhi[128][72], Blo[128][72];
};
union SharedMem { ScanSh s; GemmSh g; };

// ---------------------------------------------------------------------------
__global__ void __launch_bounds__(256) c12_kernel(const float* __restrict__ Whh12,
                                                  const float* __restrict__ hinit,
                                                  const float* __restrict__ b12,
                                                  float* __restrict__ c12) {
    int j = blockIdx.x * 256 + threadIdx.x;
    if (j >= Hn) return;
    float s = b12[j];
    const float* row = Whh12 + (size_t)j * Hn;
    for (int e = 0; e < Hn; ++e) s += row[e] * hinit[e];
    c12[j] = s;
}

// ---------------------------------------------------------------------------
__global__ void __launch_bounds__(256) tagx_kernel(const float* __restrict__ bert,
                                                   const float* __restrict__ Wtag,
                                                   const float* __restrict__ btag,
                                                   float* __restrict__ tagx) {
    int r = blockIdx.x * 4 + (threadIdx.x >> 6);
    int lane = threadIdx.x & 63;
    const float* wx = Wtag + 2 * Hn;
    const float* row = bert + (size_t)r * Hn;
    float s = 0.f;
    for (int e = lane; e < Hn; e += 64) s += row[e] * wx[e];
    #pragma unroll
    for (int m = 1; m < 64; m <<= 1) s += __shfl_xor(s, m, 64);
    if (lane == 0) tagx[r] = s + btag[0];
}

// ---------------------------------------------------------------------------
__global__ void init_qcnt(int* q, int v) {
    if (threadIdx.x < 4) q[threadIdx.x] = v;
}

// ---------------------------------------------------------------------------
__global__ void __launch_bounds__(256) split_bert(const float4* __restrict__ in,
                                                  u64* __restrict__ hi,
                                                  u64* __restrict__ lo) {
    const int stride = gridDim.x * 256;
    for (int u = blockIdx.x * 256 + threadIdx.x; u < RTn * Hn / 4; u += stride) {
        float4 v = in[u];
        float f[4] = {v.x, v.y, v.z, v.w};
        u64 uh = 0, ul = 0;
        #pragma unroll
        for (int e = 0; e < 4; ++e) {
            unsigned short h = f2bf(f[e]);
            unsigned short l = f2bf(f[e] - bf2f(h));
            uh |= (u64)h << (16 * e);
            ul |= (u64)l << (16 * e);
        }
        hi[u] = uh; lo[u] = ul;
    }
}

// ---------------------------------------------------------------------------
__global__ void __launch_bounds__(256) split_w(const float* __restrict__ W0,
                                               const float* __restrict__ W1,
                                               u64* __restrict__ whi,
                                               u64* __restrict__ wlo) {
    int u = blockIdx.x * 256 + threadIdx.x;
    constexpr int UPM = Hn * Hn / 4;
    if (u >= 2 * UPM) return;
    int mat = (u >= UPM) ? 1 : 0;
    int loc = u - mat * UPM;
    float4 v = ((const float4*)(mat ? W1 : W0))[loc];
    float f[4] = {v.x, v.y, v.z, v.w};
    u64 uh = 0, ul = 0;
    #pragma unroll
    for (int e = 0; e < 4; ++e) {
        unsigned short h = f2bf(f[e]);
        unsigned short l = f2bf(f[e] - bf2f(h));
        uh |= (u64)h << (16 * e);
        ul |= (u64)l << (16 * e);
    }
    whi[u] = uh; wlo[u] = ul;
}

// ---------------------------------------------------------------------------
// One 128x128 tile of the precompute GEMM, pre-split operands (v2 math).
// NT = block size (256 or 512). COH: agent-scope output stores (cross-XCD
// visible before the release counter) vs plain stores.
template<int NT, bool COH>
__device__ __forceinline__ void gemm_tile_v2(
        int mt, int nt, int tid,
        unsigned short (*Ahi)[72], unsigned short (*Alo)[72],
        unsigned short (*Bhi)[72], unsigned short (*Blo)[72],
        const unsigned short* bhi, const unsigned short* blo,
        const unsigned short* whi, const unsigned short* wlo,
        const float* b11, const float* c12, float* xp, float* h12) {
    const int wv = tid >> 6, lane = tid & 63;
    const int r0 = mt * 128;
    const bool second = (nt >= 6);
    const int jb = (second ? nt - 6 : nt) * 128;
    const size_t matbase = second ? (size_t)Hn * Hn : 0;

    f32x4 acc[8][2] = {};
    for (int e0 = 0; e0 < Hn; e0 += 64) {
        __syncthreads();
        #pragma unroll
        for (int i = 0; i < 2048 / NT; ++i) {
            int flat = tid + i * NT;
            int row = flat >> 4, c4 = (flat & 15) * 4;
            size_t aoff = (size_t)(r0 + row) * Hn + e0 + c4;
            size_t boff = matbase + (size_t)(jb + row) * Hn + e0 + c4;
            *(u64*)&Ahi[row][c4] = *(const u64*)(bhi + aoff);
            *(u64*)&Alo[row][c4] = *(const u64*)(blo + aoff);
            *(u64*)&Bhi[row][c4] = *(const u64*)(whi + boff);
            *(u64*)&Blo[row][c4] = *(const u64*)(wlo + boff);
        }
        __syncthreads();
        if (wv < 4) {
            #pragma unroll
            for (int kt = 0; kt < 2; ++kt) {
                const int ko  = kt * 32 + (lane >> 4) * 8;
                const int nr0 = wv * 32 + (lane & 15);
                short8v bh0 = __builtin_bit_cast(short8v, *(const uint4*)&Bhi[nr0][ko]);
                short8v bl0 = __builtin_bit_cast(short8v, *(const uint4*)&Blo[nr0][ko]);
                short8v bh1 = __builtin_bit_cast(short8v, *(const uint4*)&Bhi[nr0 + 16][ko]);
                short8v bl1 = __builtin_bit_cast(short8v, *(const uint4*)&Blo[nr0 + 16][ko]);
                #pragma unroll
                for (int m = 0; m < 8; ++m) {
                    const int ar = m * 16 + (lane & 15);
                    short8v ah = __builtin_bit_cast(short8v, *(const uint4*)&Ahi[ar][ko]);
                    short8v al = __builtin_bit_cast(short8v, *(const uint4*)&Alo[ar][ko]);
                    acc[m][0] = __builtin_amdgcn_mfma_f32_16x16x32_bf16(ah, bh0, acc[m][0], 0, 0, 0);
                    acc[m][0] = __builtin_amdgcn_mfma_f32_16x16x32_bf16(al, bh0, acc[m][0], 0, 0, 0);
                    acc[m][0] = __builtin_amdgcn_mfma_f32_16x16x32_bf16(ah, bl0, acc[m][0], 0, 0, 0);
                    acc[m][1] = __builtin_amdgcn_mfma_f32_16x16x32_bf16(ah, bh1, acc[m][1], 0, 0, 0);
                    acc[m][1] = __builtin_amdgcn_mfma_f32_16x16x32_bf16(al, bh1, acc[m][1], 0, 0, 0);
                    acc[m][1] = __builtin_amdgcn_mfma_f32_16x16x32_bf16(ah, bl1, acc[m][1], 0, 0, 0);
                }
            }
        }
    }
    if (wv < 4) {
        const int nl = lane & 15, rs = lane >> 4;
        #pragma unroll
        for (int ntf = 0; ntf < 2; ++ntf) {
            int lcol = jb + wv * 32 + ntf * 16 + nl;
            float bias = second ? c12[lcol] : b11[lcol];
            #pragma unroll
            for (int m = 0; m < 8; ++m) {
                #pragma unroll
                for (int r = 0; r < 4; ++r) {
                    int grow = r0 + m * 16 + rs * 4 + r;
                    float v = acc[m][ntf][r] + bias;
                    float res = second ? tanhf(v) : v;
                    float* dst = (second ? h12 : xp) + (size_t)grow * Hn + lcol;
                    if (COH)
                        __hip_atomic_store(dst, res, __ATOMIC_RELAXED,
                                           __HIP_MEMORY_SCOPE_AGENT);
                    else
                        *dst = res;
                }
            }
        }
    }
}

// ---------------------------------------------------------------------------
// Quarter-0 precompute: 768 blocks, mt = (bid/12)*4 (t in [0,128) per batch).
__global__ void __launch_bounds__(256, 2) gemm_q0(
        const unsigned short* __restrict__ bhi, const unsigned short* __restrict__ blo,
        const unsigned short* __restrict__ whi, const unsigned short* __restrict__ wlo,
        const float* __restrict__ b11, const float* __restrict__ c12,
        float* __restrict__ xp, float* __restrict__ h12) {
    __shared__ __align__(16) GemmSh g;
    int mt = (blockIdx.x / 12) * 4, nt = blockIdx.x % 12;
    gemm_tile_v2<256, false>(mt, nt, threadIdx.x, g.Ahi, g.Alo, g.Bhi, g.Blo,
                             bhi, blo, whi, wlo, b11, c12, xp, h12);
}

// ---------------------------------------------------------------------------
// Full fallback GEMM (operand conversion in-kernel; R16-proven).
__global__ void __launch_bounds__(256, 2) gemm_pre_mfma(
        const float* __restrict__ bert,
        const float* __restrict__ Wih11, const float* __restrict__ Wih12,
        const float* __restrict__ b11, const float* __restrict__ c12,
        float* __restrict__ xp, float* __restrict__ h12) {
    __shared__ __align__(16) GemmSh sg;
    const int tid  = threadIdx.x;
    const int wv   = tid >> 6, lane = tid & 63;
    const int mt   = blockIdx.x / 12, nt = blockIdx.x % 12;
    const int r0   = mt * 128;
    const bool second = (nt >= 6);
    const float* W = second ? Wih12 : Wih11;
    const int jb   = (second ? nt - 6 : nt) * 128;

    f32x4 acc[8][2] = {};
    for (int e0 = 0; e0 < Hn; e0 += 64) {
        __syncthreads();
        #pragma unroll
        for (int i = 0; i < 8; ++i) {
            int flat = tid + i * 256;
            int row  = flat >> 4, c4 = (flat & 15) * 4;
            float4 va = *(const float4*)(bert + (size_t)(r0 + row) * Hn + e0 + c4);
            float4 vb = *(const float4*)(W    + (size_t)(jb + row) * Hn + e0 + c4);
            float fa[4] = {va.x, va.y, va.z, va.w};
            float fb[4] = {vb.x, vb.y, vb.z, vb.w};
            u64 uah = 0, ual = 0, ubh = 0, ubl = 0;
            #pragma unroll
            for (int e = 0; e < 4; ++e) {
                unsigned short h = f2bf(fa[e]);
                unsigned short l = f2bf(fa[e] - bf2f(h));
                uah |= (u64)h << (16 * e);
                ual |= (u64)l << (16 * e);
                h = f2bf(fb[e]);
                l = f2bf(fb[e] - bf2f(h));
                ubh |= (u64)h << (16 * e);
                ubl |= (u64)l << (16 * e);
            }
            *(u64*)&sg.Ahi[row][c4] = uah;
            *(u64*)&sg.Alo[row][c4] = ual;
            *(u64*)&sg.Bhi[row][c4] = ubh;
            *(u64*)&sg.Blo[row][c4] = ubl;
        }
        __syncthreads();
        #pragma unroll
        for (int kt = 0; kt < 2; ++kt) {
            const int ko  = kt * 32 + (lane >> 4) * 8;
            const int nr0 = wv * 32 + (lane & 15);
            short8v bh0 = __builtin_bit_cast(short8v, *(const uint4*)&sg.Bhi[nr0][ko]);
            short8v bl0 = __builtin_bit_cast(short8v, *(const uint4*)&sg.Blo[nr0][ko]);
            short8v bh1 = __builtin_bit_cast(short8v, *(const uint4*)&sg.Bhi[nr0 + 16][ko]);
            short8v bl1 = __builtin_bit_cast(short8v, *(const uint4*)&sg.Blo[nr0 + 16][ko]);
            #pragma unroll
            for (int m = 0; m < 8; ++m) {
                const int ar = m * 16 + (lane & 15);
                short8v ah = __builtin_bit_cast(short8v, *(const uint4*)&sg.Ahi[ar][ko]);
                short8v al = __builtin_bit_cast(short8v, *(const uint4*)&sg.Alo[ar][ko]);
                acc[m][0] = __builtin_amdgcn_mfma_f32_16x16x32_bf16(ah, bh0, acc[m][0], 0, 0, 0);
                acc[m][0] = __builtin_amdgcn_mfma_f32_16x16x32_bf16(al, bh0, acc[m][0], 0, 0, 0);
                acc[m][0] = __builtin_amdgcn_mfma_f32_16x16x32_bf16(ah, bl0, acc[m][0], 0, 0, 0);
                acc[m][1] = __builtin_amdgcn_mfma_f32_16x16x32_bf16(ah, bh1, acc[m][1], 0, 0, 0);
                acc[m][1] = __builtin_amdgcn_mfma_f32_16x16x32_bf16(al, bh1, acc[m][1], 0, 0, 0);
                acc[m][1] = __builtin_amdgcn_mfma_f32_16x16x32_bf16(ah, bl1, acc[m][1], 0, 0, 0);
            }
        }
    }
    const int nl = lane & 15, rs = lane >> 4;
    #pragma unroll
    for (int ntf = 0; ntf < 2; ++ntf) {
        int lcol = jb + wv * 32 + ntf * 16 + nl;
        float bias = second ? c12[lcol] : b11[lcol];
        #pragma unroll
        for (int m = 0; m < 8; ++m) {
            #pragma unroll
            for (int r = 0; r < 4; ++r) {
                int grow = r0 + m * 16 + rs * 4 + r;
                float v = acc[m][ntf][r] + bias;
                if (second) h12[(size_t)grow * Hn + lcol] = tanhf(v);
                else        xp [(size_t)grow * Hn + lcol] = v;
            }
        }
    }
}

// ---------------------------------------------------------------------------
// Fused cooperative kernel: blocks 0..191 = R13/R16 scan (verbatim, plus
// quarter gates); blocks 192..255 = persistent gemm workers computing
// xp/h12 quarters 1..3 (mt = 4*gid + q), release-counting per quarter.
__global__ void __launch_bounds__(512, 1) fused_kernel(
        const float* xp, const float* h12, const float* tagx,
        const float* Whh11, const float* Wih21,
        const float* Whh21, const float* b21, const float* Wtag,
        float* pub, int* flags, int* qcnt,
        const unsigned short* bhi, const unsigned short* blo,
        const unsigned short* whi, const unsigned short* wlo,
        const float* b11, const float* c12,
        float* xpw, float* h12w, int do_gemm, float* out) {
    __shared__ __align__(16) SharedMem sh;
    const int tid = threadIdx.x;
    const int bid = blockIdx.x;

    if (bid >= 192) {
        // ---- gemm worker role ----
        if (!do_gemm) return;
        const int gid = bid - 192;
        for (int q = 1; q <= 3; ++q) {
            const int mt = 4 * gid + q;
            for (int nt = 0; nt < 12; ++nt)
                gemm_tile_v2<512, true>(mt, nt, tid,
                                        sh.g.Ahi, sh.g.Alo, sh.g.Bhi, sh.g.Blo,
                                        bhi, blo, whi, wlo, b11, c12, xpw, h12w);
            __syncthreads();
            if (tid == 0)
                __hip_atomic_fetch_add(qcnt + q, 1, __ATOMIC_RELEASE,
                                       __HIP_MEMORY_SCOPE_AGENT);
        }
        return;
    }

    // ---- scan role (R13/R16 verbatim + quarter gates) ----
    unsigned short* planes = sh.s.planes;
    float (*redbuf)[4][64][4] = sh.s.redbuf;
    float* wt1 = sh.s.wt1;
    float* wt2 = sh.s.wt2;
    float* tagbuf = sh.s.tagbuf;

    const int wv   = tid >> 6;          // wave 0..7
    const int lane = tid & 63;
    const int g    = bid & 7;           // group (XCD round-robin heuristic)
    const int prod = bid >> 3;          // col-block 0..23

    // loop-invariant: B-fragments (hi/lo bf16), 36 frags = 144 VGPR
    short8v wb[3][3][2][2];             // [mat][ktl][nt][hi/lo]
    {
        #pragma unroll
        for (int mt = 0; mt < 3; ++mt) {
            const float* Wmat = (mt == 0) ? Whh11 : (mt == 1) ? Wih21 : Whh21;
            #pragma unroll
            for (int ktl = 0; ktl < 3; ++ktl) {
                #pragma unroll
                for (int nt = 0; nt < 2; ++nt) {
                    int gcol = prod * 32 + nt * 16 + (lane & 15);
                    int k0   = (wv * 3 + ktl) * 32 + (lane >> 4) * 8;
                    const float* p = Wmat + (size_t)gcol * Hn + k0;
                    float4 f0 = *(const float4*)p;
                    float4 f1 = *(const float4*)(p + 4);
                    float fv[8] = {f0.x, f0.y, f0.z, f0.w, f1.x, f1.y, f1.z, f1.w};
                    union { short8v v; unsigned short u[8]; } hi, lo;
                    #pragma unroll
                    for (int i = 0; i < 8; ++i) {
                        unsigned short h = f2bf(fv[i]);
                        hi.u[i] = h;
                        lo.u[i] = f2bf(fv[i] - bf2f(h));
                    }
                    wb[mt][ktl][nt][0] = hi.v;
                    wb[mt][ktl][nt][1] = lo.v;
                }
            }
        }
    }
    for (int i = tid; i < Hn; i += 512) { wt1[i] = Wtag[i]; wt2[i] = Wtag[Hn + i]; }
    const int ecol = prod * 32 + (tid & 31);     // epilogue col for tid<256
    const float bias21 = b21[ecol];

    // zero planes once (rows 8-15 stay zero; rows 0-7 overwritten each step)
    for (int i = tid; i < 4 * PSZ / 2; i += 512) ((unsigned int*)planes)[i] = 0u;

    float* outO   = out;
    float* outH2  = out + RTn;
    float* outTag = out + RTn + (size_t)RTn * Hn;
    int* myflag = flags + (g * NPROD + prod) * FSTR;
    float h2c = 0.f;                    // fp32 carry (tid<256)
    __syncthreads();

    for (int t = 0; t < Tn; ++t) {
        // quarter gate (acquire xp/h12 for t in [q*128,(q+1)*128))
        if (t != 0 && (t & 127) == 0) {
            const int q = t >> 7;
            if (tid == 0) {
                while (__hip_atomic_load(qcnt + q, __ATOMIC_ACQUIRE,
                                         __HIP_MEMORY_SCOPE_AGENT) < 64)
                    __builtin_amdgcn_s_sleep(8);
            }
            __syncthreads();
            (void)__hip_atomic_load(qcnt + q, __ATOMIC_ACQUIRE,
                                    __HIP_MEMORY_SCOPE_AGENT);
        }

        // flag-independent prefetch
        float xpv = 0.f, h12pv = 0.f, tgxv = 0.f;
        if (tid < 256) {
            int m = tid >> 5;
            size_t rr = (size_t)(g * 8 + m) * Tn + t;
            xpv   = xp  [rr * Hn + ecol];
            h12pv = h12 [rr * Hn + ecol];
            tgxv  = tagx[rr];
        }

        // spin: 24 parallel pollers (fast-path discovery only)
        if (tid < NPROD) {
            const int* f = flags + (g * NPROD + tid) * FSTR;
            while (__hip_atomic_load(f, __ATOMIC_RELAXED,
                                     __HIP_MEMORY_SCOPE_AGENT) < t)
                __builtin_amdgcn_s_sleep(2);
        }
        __syncthreads();   // A

        // bulk gather 48 KB (MLP), validate seq nibbles, re-fetch stale only
        {
            const u64* pubc =
                (const u64*)(pub + (size_t)(t & 3) * SSTR + g * GSTR);
            const unsigned sq = (unsigned)(t & 15);
            u64 v[12];
            #pragma unroll
            for (int i = 0; i < 12; ++i)
                v[i] = __hip_atomic_load(pubc + tid + i * 512, __ATOMIC_RELAXED,
                                         __HIP_MEMORY_SCOPE_AGENT);
            unsigned pend = 0;
            #pragma unroll
            for (int i = 0; i < 12; ++i)
                if ((unsigned)((v[i] >> 48) & 15ull) != sq) pend |= (1u << i);
            while (__builtin_expect(pend != 0, 0)) {
                __builtin_amdgcn_s_sleep(1);
                #pragma unroll
                for (int i = 0; i < 12; ++i)
                    if (pend & (1u << i))
                        v[i] = __hip_atomic_load(pubc + tid + i * 512,
                                                 __ATOMIC_RELAXED,
                                                 __HIP_MEMORY_SCOPE_AGENT);
                unsigned np = 0;
                #pragma unroll
                for (int i = 0; i < 12; ++i)
                    if ((pend & (1u << i)) &&
                        (unsigned)((v[i] >> 48) & 15ull) != sq) np |= (1u << i);
                pend = np;
            }
            #pragma unroll
            for (int i = 0; i < 12; ++i) {
                int idx = tid + i * 512;
                int p = idx >> 8, rem = idx & 255;
                int m = rem >> 5, jc = rem & 31;
                int base = m * PITCH + p * 32 + jc;
                u64 u = v[i];
                planes[0 * PSZ + base] = (unsigned short)(u & 0xFFFF);
                planes[1 * PSZ + base] = (unsigned short)((u >> 16) & 0xFFFF);
                planes[2 * PSZ + base] = (unsigned short)((u >> 32) & 0xFFFF);
                planes[3 * PSZ + base] = (unsigned short)((u >> 48) & 0xFFF0);
            }
        }
        __syncthreads();   // B: planes staged

        // gate-dot: wave wv = batch wv; lane covers k = lane*12 .. +12
        {
            const int kb = lane * 12;
            float s = 0.f;
            #pragma unroll
            for (int part = 0; part < 3; ++part) {
                int off = wv * PITCH + kb + part * 4;
                u64 u1h = *(const u64*)&planes[0 * PSZ + off];
                u64 u1l = *(const u64*)&planes[1 * PSZ + off];
                u64 u2h = *(const u64*)&planes[2 * PSZ + off];
                u64 u2l = *(const u64*)&planes[3 * PSZ + off];
                #pragma unroll
                for (int e = 0; e < 4; ++e) {
                    int k = kb + part * 4 + e;
                    float h1 = bf2f((unsigned short)(u1h >> (16 * e)))
                             + bf2f((unsigned short)(u1l >> (16 * e)));
                    float h2 = bf2f((unsigned short)(u2h >> (16 * e)))
                             + bf2f((unsigned short)(u2l >> (16 * e)));
                    s = fmaf(h1, wt1[k], s);
                    s = fmaf(h2, wt2[k], s);
                }
            }
            #pragma unroll
            for (int mm = 1; mm < 64; mm <<= 1) s += __shfl_xor(s, mm, 64);
            if (lane == 0) tagbuf[wv] = s;
        }

        // MFMA matvec: wave wv covers K-tiles wv*3..+3
        {
            f32x4 a00 = {0.f,0.f,0.f,0.f}, a01 = {0.f,0.f,0.f,0.f};
            f32x4 a10 = {0.f,0.f,0.f,0.f}, a11v = {0.f,0.f,0.f,0.f};
            const int ar = (lane & 15) * PITCH + (lane >> 4) * 8;
            #pragma unroll
            for (int ktl = 0; ktl < 3; ++ktl) {
                const int ko = (wv * 3 + ktl) * 32 + ar;
                short8v h1h = __builtin_bit_cast(short8v, *(const uint4*)&planes[0 * PSZ + ko]);
                short8v h1l = __builtin_bit_cast(short8v, *(const uint4*)&planes[1 * PSZ + ko]);
                short8v h2h = __builtin_bit_cast(short8v, *(const uint4*)&planes[2 * PSZ + ko]);
                short8v h2l = __builtin_bit_cast(short8v, *(const uint4*)&planes[3 * PSZ + ko]);
                a00 = __builtin_amdgcn_mfma_f32_16x16x32_bf16(h1h, wb[0][ktl][0][0], a00, 0, 0, 0);
                a00 = __builtin_amdgcn_mfma_f32_16x16x32_bf16(h1l, wb[0][ktl][0][0], a00, 0, 0, 0);
                a00 = __builtin_amdgcn_mfma_f32_16x16x32_bf16(h1h, wb[0][ktl][0][1], a00, 0, 0, 0);
                a01 = __builtin_amdgcn_mfma_f32_16x16x32_bf16(h1h, wb[0][ktl][1][0], a01, 0, 0, 0);
                a01 = __builtin_amdgcn_mfma_f32_16x16x32_bf16(h1l, wb[0][ktl][1][0], a01, 0, 0, 0);
                a01 = __builtin_amdgcn_mfma_f32_16x16x32_bf16(h1h, wb[0][ktl][1][1], a01, 0, 0, 0);
                a10 = __builtin_amdgcn_mfma_f32_16x16x32_bf16(h1h, wb[1][ktl][0][0], a10, 0, 0, 0);
                a10 = __builtin_amdgcn_mfma_f32_16x16x32_bf16(h1l, wb[1][ktl][0][0], a10, 0, 0, 0);
                a10 = __builtin_amdgcn_mfma_f32_16x16x32_bf16(h1h, wb[1][ktl][0][1], a10, 0, 0, 0);
                a11v = __builtin_amdgcn_mfma_f32_16x16x32_bf16(h1h, wb[1][ktl][1][0], a11v, 0, 0, 0);
                a11v = __builtin_amdgcn_mfma_f32_16x16x32_bf16(h1l, wb[1][ktl][1][0], a11v, 0, 0, 0);
                a11v = __builtin_amdgcn_mfma_f32_16x16x32_bf16(h1h, wb[1][ktl][1][1], a11v, 0, 0, 0);
                a10 = __builtin_amdgcn_mfma_f32_16x16x32_bf16(h2h, wb[2][ktl][0][0], a10, 0, 0, 0);
                a10 = __builtin_amdgcn_mfma_f32_16x16x32_bf16(h2l, wb[2][ktl][0][0], a10, 0, 0, 0);
                a10 = __builtin_amdgcn_mfma_f32_16x16x32_bf16(h2h, wb[2][ktl][0][1], a10, 0, 0, 0);
                a11v = __builtin_amdgcn_mfma_f32_16x16x32_bf16(h2h, wb[2][ktl][1][0], a11v, 0, 0, 0);
                a11v = __builtin_amdgcn_mfma_f32_16x16x32_bf16(h2l, wb[2][ktl][1][0], a11v, 0, 0, 0);
                a11v = __builtin_amdgcn_mfma_f32_16x16x32_bf16(h2h, wb[2][ktl][1][1], a11v, 0, 0, 0);
            }
            *(f32x4*)&redbuf[wv][0][lane][0] = a00;
            *(f32x4*)&redbuf[wv][1][lane][0] = a01;
            *(f32x4*)&redbuf[wv][2][lane][0] = a10;
            *(f32x4*)&redbuf[wv][3][lane][0] = a11v;
        }
        __syncthreads();   // C: redbuf + tagbuf ready

        // epilogue: tid<256 = (batch m, col jc); publish seq-tagged u64
        float o = 0.f, tg = 0.f, h2nv = 0.f;
        if (tid < 256) {
            int m = tid >> 5, jc = tid & 31;
            int n = jc & 15, nt = jc >> 4;
            int rl = (m >> 2) * 16 + n, rg = m & 3;
            float f11 = 0.f, f21 = 0.f;
            #pragma unroll
            for (int w = 0; w < 8; ++w) {
                f11 += redbuf[w][nt][rl][rg];
                f21 += redbuf[w][2 + nt][rl][rg];
            }
            tg = tagbuf[m] + tgxv;
            o  = 1.f / (1.f + expf(-tg));
            float h11v = tanhf(xpv + f11);
            float h21v = tanhf(f21 + bias21);
            float h1nv = h11v * (1.f - o) + h12pv * o;
            h2nv = h2c * (1.f - o) + h21v * o;
            h2c = h2nv;
            unsigned short h1h = f2bf(h1nv);
            unsigned short h1l = f2bf(h1nv - bf2f(h1h));
            unsigned short h2h = f2bf(h2nv);
            unsigned short h2l = f2bf(h2nv - bf2f(h2h));
            unsigned short h2q = (unsigned short)((h2l & 0xFFF0)
                                                  | (unsigned)((t + 1) & 15));
            u64 u = (u64)h1h | ((u64)h1l << 16) | ((u64)h2h << 32)
                  | ((u64)h2q << 48);
            u64* pn = (u64*)(pub + (size_t)((t + 1) & 3) * SSTR + g * GSTR)
                    + prod * 256 + m * 32 + jc;
            __hip_atomic_store(pn, u, __ATOMIC_RELAXED, __HIP_MEMORY_SCOPE_AGENT);
        }
        __syncthreads();   // D: drains publish stores (fast-path ordering)
        if (tid == 0)
            __hip_atomic_store(myflag, t + 1, __ATOMIC_RELAXED,
                               __HIP_MEMORY_SCOPE_AGENT);
        // outputs after the flag — off the inter-block critical chain
        if (tid < 256) {
            int m = tid >> 5;
            size_t rr = (size_t)(g * 8 + m) * Tn + t;
            outH2[rr * Hn + ecol] = h2nv;
            if ((tid & 31) == 0 && prod == 0) { outO[rr] = o; outTag[rr] = tg; }
        }
    }
}

// ---------------------------------------------------------------------------
extern "C" void kernel_launch(void* const* d_in, const int* in_sizes, int n_in,
                              void* d_out, int out_size, void* d_ws, size_t ws_size,
                              hipStream_t stream) {
    const float* bert  = (const float*)d_in[0];
    const float* Wih11 = (const float*)d_in[1];
    const float* Whh11 = (const float*)d_in[2];
    const float* b11   = (const float*)d_in[3];
    const float* Wih12 = (const float*)d_in[4];
    const float* Whh12 = (const float*)d_in[5];
    const float* b12   = (const float*)d_in[6];
    const float* Wih21 = (const float*)d_in[7];
    const float* Whh21 = (const float*)d_in[8];
    const float* b21   = (const float*)d_in[9];
    const float* Wtag  = (const float*)d_in[10];
    const float* btag  = (const float*)d_in[11];
    const float* hinit = (const float*)d_in[12];
    float* ws = (float*)d_ws;
    float* xp    = ws + OFF_XP;
    float* h12   = ws + OFF_H12;
    float* tagx  = ws + OFF_TAGX;
    float* c12   = ws + OFF_C12;
    float* pub   = ws + OFF_PUB;
    int*   flags = (int*)(ws + OFF_FLAGS);
    int*   qcnt  = (int*)(ws + OFF_QCNT);
    float* out   = (float*)d_out;

    hipMemsetAsync(pub,   0, (size_t)SLOTS * SSTR * sizeof(float), stream);
    hipMemsetAsync(flags, 0, NGRP * NPROD * FSTR * sizeof(int), stream);

    c12_kernel<<<3, 256, 0, stream>>>(Whh12, hinit, b12, c12);

    const bool use_split = ws_size >= NEED_FLT * sizeof(float);
    unsigned short* bhi = (unsigned short*)(ws + OFF_BHI);
    unsigned short* blo = (unsigned short*)(ws + OFF_BLO);
    unsigned short* whi = (unsigned short*)(ws + OFF_WHI);
    unsigned short* wlo = (unsigned short*)(ws + OFF_WLO);
    int do_gemm;
    if (use_split) {
        init_qcnt<<<1, 4, 0, stream>>>(qcnt, 0);
        split_bert<<<4096, 256, 0, stream>>>((const float4*)bert,
                                             (u64*)bhi, (u64*)blo);
        split_w<<<1152, 256, 0, stream>>>(Wih11, Wih12, (u64*)whi, (u64*)wlo);
        gemm_q0<<<768, 256, 0, stream>>>(bhi, blo, whi, wlo, b11, c12, xp, h12);
        do_gemm = 1;
    } else {
        init_qcnt<<<1, 4, 0, stream>>>(qcnt, 64);
        gemm_pre_mfma<<<256 * 12, 256, 0, stream>>>(bert, Wih11, Wih12, b11,
                                                    c12, xp, h12);
        do_gemm = 0;
    }
    tagx_kernel<<<RTn / 4, 256, 0, stream>>>(bert, Wtag, btag, tagx);

    const float* xp_c  = xp;
    const float* h12_c = h12;
    void* params[] = { &xp_c, &h12_c, &tagx, &Whh11, &Wih21, &Whh21, &b21,
                       &Wtag, &pub, &flags, &qcnt, &bhi, &blo, &whi, &wlo,
                       &b11, &c12, &xp, &h12, &do_gemm, &out };
    hipLaunchCooperativeKernel((void*)fused_kernel, dim3(256), dim3(512),
                               params, 0, stream);
}